// Round 8
// baseline (458.774 us; speedup 1.0000x reference)
//
#include <hip/hip_runtime.h>
#include <hip/hip_bf16.h>

#define BB 4
#define SS 1024
#define DD 1024
#define HH 16

typedef __attribute__((ext_vector_type(8))) short bf16x8;
typedef __attribute__((ext_vector_type(4))) float f32x4;
typedef unsigned int u32;
typedef unsigned long long u64;

__device__ __forceinline__ ushort f2bf(float f) {
    u32 u = __builtin_bit_cast(u32, f);
    u32 r = (u + 0x7fffu + ((u >> 16) & 1u)) >> 16;
    return (ushort)r;
}
__device__ __forceinline__ float bf2f(ushort h) {
    return __builtin_bit_cast(float, (u32)h << 16);
}

__device__ __forceinline__ void gload16(const ushort* g, ushort* l) {
    __builtin_amdgcn_global_load_lds(
        (const __attribute__((address_space(1))) u32*)(const void*)g,
        (__attribute__((address_space(3))) u32*)(void*)l, 16, 0, 0);
}

// ---------------- convert f32 -> bf16 hi + lo residual ----------------
__global__ __launch_bounds__(256) void cvt_split(const float* __restrict__ in,
                                                 ushort* __restrict__ hi,
                                                 ushort* __restrict__ lo, int n) {
    int i = (blockIdx.x * 256 + threadIdx.x) * 4;
    if (i < n) {
        float4 v = *(const float4*)(in + i);
        ushort4 h, l;
        float* pv = (float*)&v;
        ushort* ph = (ushort*)&h;
        ushort* pl = (ushort*)&l;
#pragma unroll
        for (int j = 0; j < 4; ++j) {
            ushort hh = f2bf(pv[j]);
            ph[j] = hh;
            pl[j] = f2bf(pv[j] - bf2f(hh));
        }
        *(ushort4*)(hi + i) = h;
        *(ushort4*)(lo + i) = l;
    }
}

// ---------------- transpose W (f32 DxD) -> bf16 W^T hi/lo ----------------
__global__ __launch_bounds__(256) void transposeW_split(
    const float* __restrict__ Wq, const float* __restrict__ Wk,
    ushort* __restrict__ WqTh, ushort* __restrict__ WqTl,
    ushort* __restrict__ WkTh, ushort* __restrict__ WkTl) {
    __shared__ float tile[64][65];
    const float* W = blockIdx.z ? Wk : Wq;
    ushort* WTh = blockIdx.z ? WkTh : WqTh;
    ushort* WTl = blockIdx.z ? WkTl : WqTl;
    int kb = blockIdx.y * 64, nb = blockIdx.x * 64;
    int tid = threadIdx.x;
    int tx = tid & 63, ty = tid >> 6;
#pragma unroll
    for (int i = 0; i < 16; ++i) {
        int kl = ty * 16 + i;
        tile[kl][tx] = W[(size_t)(kb + kl) * DD + nb + tx];
    }
    __syncthreads();
#pragma unroll
    for (int i = 0; i < 16; ++i) {
        int nl = ty * 16 + i;
        float v = tile[tx][nl];
        ushort hh = f2bf(v);
        size_t idx = (size_t)(nb + nl) * DD + kb + tx;
        WTh[idx] = hh;
        WTl[idx] = f2bf(v - bf2f(hh));
    }
}

// ---------------- pack mask to bits ----------------
__global__ __launch_bounds__(256) void pack_mask(const int* __restrict__ mask,
                                                 u64* __restrict__ bits, int nwords) {
    int gw = (int)((blockIdx.x * 256 + threadIdx.x) >> 6);
    int lane = threadIdx.x & 63;
    if (gw < nwords) {
        int v = mask[(size_t)gw * 64 + lane];
        u64 m = __ballot(v != 0);
        if (lane == 0) bits[gw] = m;
    }
}

// ---------------- transpose k_hi per head-tile into tiled kT ----------------
__global__ __launch_bounds__(256) void transposeK(const ushort* __restrict__ kh,
                                                  ushort* __restrict__ kT) {
    __shared__ ushort t[64 * 66];
    int blk = blockIdx.x;
    const ushort* src = kh + (size_t)blk * 4096;
    ushort* dst = kT + (size_t)blk * 4096;
    int tid = threadIdx.x;
#pragma unroll
    for (int i = 0; i < 2; ++i) {
        int c = tid + 256 * i;
        int r = c >> 3, col = (c & 7) << 3;
        uint4 v = *(const uint4*)(src + (size_t)c * 8);
        const uint* pv = (const uint*)&v;
        *(uint*)(t + r * 66 + col + 0) = pv[0];
        *(uint*)(t + r * 66 + col + 2) = pv[1];
        *(uint*)(t + r * 66 + col + 4) = pv[2];
        *(uint*)(t + r * 66 + col + 6) = pv[3];
    }
    __syncthreads();
#pragma unroll
    for (int i = 0; i < 2; ++i) {
        int c = tid + 256 * i;
        int d = c >> 3, k0 = (c & 7) << 3;
        uint4 o;
        ushort* po = (ushort*)&o;
#pragma unroll
        for (int j = 0; j < 8; ++j) po[j] = t[(k0 + j) * 66 + d];
        *(uint4*)(dst + d * 64 + k0) = o;
    }
}

// ---------------- split-precision projection GEMM (BM=64, 2 blocks/CU) ----------------
template <int MODE>
__global__ __launch_bounds__(256) void gemm_proj(
    const ushort* __restrict__ Ah, const ushort* __restrict__ Al,
    const ushort* __restrict__ Bh, const ushort* __restrict__ Bl,
    const float* __restrict__ bias, const float* __restrict__ wcomb,
    ushort* __restrict__ Chi, ushort* __restrict__ Clo, ushort* __restrict__ Cw) {
    __shared__ __align__(16) ushort As[64 * 64];    // 8 KB
    __shared__ __align__(16) ushort Bs[128 * 64];   // 16 KB
    const int tn = blockIdx.x, tm = blockIdx.y;     // tn<8, tm<64
    const int tid = threadIdx.x, lane = tid & 63, w = tid >> 6;
    const int lr = lane >> 4, lc = lane & 15;
    f32x4 acc[8];
#pragma unroll
    for (int n = 0; n < 8; ++n) acc[n] = (f32x4){0.f, 0.f, 0.f, 0.f};

    for (int kt = 0; kt < 3 * DD; kt += 64) {
        int sec = kt >> 10;
        int kcol = kt & (DD - 1);
        const ushort* Asel = (sec == 2) ? Al : Ah;  // [hi, hi, lo]
        const ushort* Bsel = (sec == 1) ? Bl : Bh;  // [hi, lo, hi]
        __syncthreads();
#pragma unroll
        for (int i = 0; i < 2; ++i) {
            int c = tid + 256 * i;
            int r = c >> 3, col = (c & 7) << 3;
            gload16(Asel + (size_t)(tm * 64 + r) * DD + kcol + col,
                    As + (w * 64 + 256 * i) * 8);
        }
#pragma unroll
        for (int i = 0; i < 4; ++i) {
            int c = tid + 256 * i;
            int r = c >> 3, col = (c & 7) << 3;
            gload16(Bsel + (size_t)(tn * 128 + r) * DD + kcol + col,
                    Bs + (w * 64 + 256 * i) * 8);
        }
        __syncthreads();
        const ushort* Aw = As + (w * 16) * 64;  // wave w owns rows w*16..w*16+15
#pragma unroll
        for (int t = 0; t < 2; ++t) {
            bf16x8 af = *(const bf16x8*)(Aw + lc * 64 + t * 32 + lr * 8);
#pragma unroll
            for (int n = 0; n < 8; ++n) {
                bf16x8 bfr = *(const bf16x8*)(Bs + (n * 16 + lc) * 64 + t * 32 + lr * 8);
                acc[n] = __builtin_amdgcn_mfma_f32_16x16x32_bf16(af, bfr, acc[n], 0, 0, 0);
            }
        }
    }
#pragma unroll
    for (int n = 0; n < 8; ++n) {
        int gcol = tn * 128 + n * 16 + lc;
#pragma unroll
        for (int r = 0; r < 4; ++r) {
            int grow = tm * 64 + w * 16 + lr * 4 + r;
            float v = acc[n][r] + bias[gcol];
            size_t idx = (size_t)grow * DD + gcol;
            ushort hh = f2bf(v);
            Chi[idx] = hh;
            Clo[idx] = f2bf(v - bf2f(hh));
            if (MODE == 0) Cw[idx] = f2bf(v * wcomb[(grow >> 6) & 15]);
        }
    }
}

// ---------------- combined-scores GEMM (head-block K) ----------------
__global__ __launch_bounds__(256) void gemm_comb(
    const ushort* __restrict__ Aq, const ushort* __restrict__ Bk,
    const float* __restrict__ bias, float* __restrict__ Cf) {
    __shared__ __align__(16) ushort As[128 * 64];
    __shared__ __align__(16) ushort Bs[128 * 64];
    const int bz = blockIdx.z;
    const ushort* Ab = Aq + (size_t)bz * SS * DD;
    const ushort* Bb = Bk + (size_t)bz * SS * DD;
    const int tn = blockIdx.x, tm = blockIdx.y;
    const int tid = threadIdx.x, lane = tid & 63, w = tid >> 6;
    const int wm = w >> 1, wn = w & 1;
    const int lr = lane >> 4, lc = lane & 15;
    f32x4 acc[4][4];
#pragma unroll
    for (int m = 0; m < 4; ++m)
#pragma unroll
        for (int n = 0; n < 4; ++n) acc[m][n] = (f32x4){0.f, 0.f, 0.f, 0.f};

    for (int h = 0; h < HH; ++h) {
        __syncthreads();
        const ushort* Asrc = Ab + (size_t)h * 65536 + tm * 8192;
        const ushort* Bsrc = Bb + (size_t)h * 65536 + tn * 8192;
#pragma unroll
        for (int i = 0; i < 4; ++i) {
            int c = tid + 256 * i;
            gload16(Asrc + (size_t)c * 8, As + (w * 64 + 256 * i) * 8);
        }
#pragma unroll
        for (int i = 0; i < 4; ++i) {
            int c = tid + 256 * i;
            gload16(Bsrc + (size_t)c * 8, Bs + (w * 64 + 256 * i) * 8);
        }
        __syncthreads();
        const ushort* Aw = As + (wm * 64) * 64;
        const ushort* Bw = Bs + (wn * 64) * 64;
#pragma unroll
        for (int t = 0; t < 2; ++t) {
            bf16x8 af[4], bfr[4];
#pragma unroll
            for (int m = 0; m < 4; ++m)
                af[m] = *(const bf16x8*)(Aw + (m * 16 + lc) * 64 + t * 32 + lr * 8);
#pragma unroll
            for (int n = 0; n < 4; ++n)
                bfr[n] = *(const bf16x8*)(Bw + (n * 16 + lc) * 64 + t * 32 + lr * 8);
#pragma unroll
            for (int m = 0; m < 4; ++m)
#pragma unroll
                for (int n = 0; n < 4; ++n)
                    acc[m][n] = __builtin_amdgcn_mfma_f32_16x16x32_bf16(af[m], bfr[n], acc[m][n], 0, 0, 0);
        }
    }
    float b0 = bias[0];
#pragma unroll
    for (int m = 0; m < 4; ++m) {
        int grow0 = tm * 128 + wm * 64 + m * 16 + lr * 4;
#pragma unroll
        for (int n = 0; n < 4; ++n) {
            int gcol = tn * 128 + wn * 64 + n * 16 + lc;
#pragma unroll
            for (int r = 0; r < 4; ++r)
                Cf[(size_t)bz * SS * SS + (size_t)(grow0 + r) * SS + gcol] = acc[m][n][r] + b0;
        }
    }
}

// swizzled LDS frag address (ushort units): row rr, 16B-block bi
#define SWZ(rr, bi) (((rr) << 6) + ((((bi) ^ ((rr) & 7))) << 3))

// ---------------- fused flash attention (V = K), 4 waves, LDS 41.4KB ----------------
// kh/kT staged to LDS (swizzled src); kl double-buffered in REGISTERS,
// loads issued one tile ahead (resident by the tile-end barrier's vmcnt drain).
__global__ __launch_bounds__(256) void attn_fused(
    const ushort* __restrict__ qh_, const ushort* __restrict__ ql_,
    const ushort* __restrict__ kh_, const ushort* __restrict__ kl_,
    const ushort* __restrict__ kT_, const u64* __restrict__ mbits,
    float* __restrict__ ctx) {
    __shared__ __align__(16) ushort Kb[2][2][4096];  // [buf][kh,kT]  32 KB
    __shared__ __align__(16) ushort Ps[4][16 * 68];  // 8.5 KB
    const int qt = blockIdx.x, h = blockIdx.y, b = blockIdx.z;
    const int tid = threadIdx.x, lane = tid & 63, w = tid >> 6;
    const int lr = lane >> 4, lc = lane & 15;
    const int bh = b * HH + h;
    const size_t headbase = (size_t)bh * (SS * 64);

    auto stage = [&](int buf, int kt) {
#pragma unroll
        for (int i = 0; i < 2; ++i) {
            int ch = (w << 1) + i;                      // chunk 0..7
            int row = (ch << 3) + (lane >> 3);          // 0..63
            int blkk = (lane & 7) ^ ((lane >> 3) & 7);  // swizzled 16B block
            size_t g = ((size_t)bh * 16 + kt) * 4096 + (size_t)row * 64 + blkk * 8;
            gload16(kh_ + g, &Kb[buf][0][ch * 512]);
            gload16(kT_ + g, &Kb[buf][1][ch * 512]);
        }
    };
    auto loadkl = [&](int kt, bf16x8 (&dst)[2][4]) {
        const ushort* klb = kl_ + headbase + ((size_t)kt << 12);
#pragma unroll
        for (int t = 0; t < 2; ++t)
#pragma unroll
            for (int nt = 0; nt < 4; ++nt)
                dst[t][nt] = *(const bf16x8*)(klb + (nt * 16 + lc) * 64 + t * 32 + lr * 8);
    };

    bf16x8 qfh[2], qfl[2];
    {
        size_t rowoff = headbase + (size_t)(qt * 64 + w * 16 + lc) * 64;
#pragma unroll
        for (int t = 0; t < 2; ++t) {
            qfh[t] = *(const bf16x8*)(qh_ + rowoff + t * 32 + lr * 8);
            qfl[t] = *(const bf16x8*)(ql_ + rowoff + t * 32 + lr * 8);
        }
    }
    f32x4 acc[4];
#pragma unroll
    for (int dt = 0; dt < 4; ++dt) acc[dt] = (f32x4){0.f, 0.f, 0.f, 0.f};
    float mrow[4] = {-3e38f, -3e38f, -3e38f, -3e38f};
    float lsum[4] = {0.f, 0.f, 0.f, 0.f};

    bf16x8 klA[2][4], klB[2][4];
    stage(0, 0);
    loadkl(0, klA);
    __syncthreads();

    // one tile: uses klC (current), prefetches kl for kt+1 into klN
    auto phase = [&](int kt, int buf, bf16x8 (&klC)[2][4], bf16x8 (&klN)[2][4]) {
        if (kt < 15) {
            stage(buf ^ 1, kt + 1);   // kh/kT -> LDS (next tile)
            loadkl(kt + 1, klN);      // kl -> regs (next tile)
        }
        const ushort* Bh = &Kb[buf][0][0];
        const ushort* Vt = &Kb[buf][1][0];

        // QK^T (split precision): s = qh*kh + qh*kl + ql*kh
        f32x4 sc[4];
#pragma unroll
        for (int nt = 0; nt < 4; ++nt) {
            f32x4 z = (f32x4){0.f, 0.f, 0.f, 0.f};
            __builtin_amdgcn_s_setprio(1);
#pragma unroll
            for (int t = 0; t < 2; ++t) {
                bf16x8 kfh = *(const bf16x8*)(Bh + SWZ(nt * 16 + lc, t * 4 + lr));
                z = __builtin_amdgcn_mfma_f32_16x16x32_bf16(qfh[t], kfh, z, 0, 0, 0);
                z = __builtin_amdgcn_mfma_f32_16x16x32_bf16(qfh[t], klC[t][nt], z, 0, 0, 0);
                z = __builtin_amdgcn_mfma_f32_16x16x32_bf16(qfl[t], kfh, z, 0, 0, 0);
            }
            __builtin_amdgcn_s_setprio(0);
            sc[nt] = z;
        }

        // mask + online softmax (row lr*4+r lives in a contiguous 16-lane group)
#pragma unroll
        for (int r = 0; r < 4; ++r) {
            u64 wbit = mbits[((size_t)b * SS + qt * 64 + w * 16 + lr * 4 + r) * 16 + kt];
            float rmax = -3e38f;
#pragma unroll
            for (int nt = 0; nt < 4; ++nt) {
                int kkloc = nt * 16 + lc;
                float v = sc[nt][r];
                v = ((wbit >> kkloc) & 1ULL) ? v : -3e38f;
                sc[nt][r] = v;
                rmax = fmaxf(rmax, v);
            }
#pragma unroll
            for (int d2 = 1; d2 < 16; d2 <<= 1) rmax = fmaxf(rmax, __shfl_xor(rmax, d2, 64));
            float mnew = fmaxf(mrow[r], rmax);
            float scale = __expf(mrow[r] - mnew);
            float rsum = 0.f;
#pragma unroll
            for (int nt = 0; nt < 4; ++nt) {
                float p = __expf(sc[nt][r] - mnew);
                sc[nt][r] = p;
                rsum += p;
            }
#pragma unroll
            for (int d2 = 1; d2 < 16; d2 <<= 1) rsum += __shfl_xor(rsum, d2, 64);
            lsum[r] = lsum[r] * scale + rsum;
            mrow[r] = mnew;
#pragma unroll
            for (int dt = 0; dt < 4; ++dt) acc[dt][r] *= scale;
        }

        // P -> per-wave LDS (C/D layout -> A-frag layout), pitch 68
        ushort* P = &Ps[w][0];
#pragma unroll
        for (int nt = 0; nt < 4; ++nt)
#pragma unroll
            for (int r = 0; r < 4; ++r)
                P[(lr * 4 + r) * 68 + nt * 16 + lc] = f2bf(sc[nt][r]);
        asm volatile("s_waitcnt lgkmcnt(0)" ::: "memory");
        __builtin_amdgcn_sched_barrier(0);

        bf16x8 pf[2];
#pragma unroll
        for (int t = 0; t < 2; ++t)
            pf[t] = *(const bf16x8*)(P + lc * 68 + t * 32 + lr * 8);

        // PV: context += P @ K_tile (V = K hi, from pre-transposed kT)
        __builtin_amdgcn_s_setprio(1);
#pragma unroll
        for (int dt = 0; dt < 4; ++dt) {
#pragma unroll
            for (int t = 0; t < 2; ++t) {
                bf16x8 vf = *(const bf16x8*)(Vt + SWZ(dt * 16 + lc, t * 4 + lr));
                acc[dt] = __builtin_amdgcn_mfma_f32_16x16x32_bf16(pf[t], vf, acc[dt], 0, 0, 0);
            }
        }
        __builtin_amdgcn_s_setprio(0);

        if (kt < 15) __syncthreads();  // drains vmcnt: LDS stage + klN regs resident
    };

#pragma unroll
    for (int kt2 = 0; kt2 < 16; kt2 += 2) {
        phase(kt2 + 0, 0, klA, klB);
        phase(kt2 + 1, 1, klB, klA);
    }

    // epilogue: output context layout is (B, H, S, DK) contiguous (reference reshape)
#pragma unroll
    for (int r = 0; r < 4; ++r) {
        float l = lsum[r];
        float inv = (l > 0.f) ? 1.f / l : 0.f;
        int q = qt * 64 + w * 16 + lr * 4 + r;
#pragma unroll
        for (int dt = 0; dt < 4; ++dt)
            ctx[(((size_t)bh) * SS + q) * 64 + dt * 16 + lc] = acc[dt][r] * inv;
    }
}

// ---------------- row softmax for probs ----------------
__global__ __launch_bounds__(256) void softmax_rows(float* __restrict__ data) {
    int w = threadIdx.x >> 6, lane = threadIdx.x & 63;
    float* p = data + ((size_t)blockIdx.x * 4 + w) * SS;
    float4 v[4];
    float mx = -3e38f;
#pragma unroll
    for (int i = 0; i < 4; ++i) {
        v[i] = *(const float4*)(p + i * 256 + lane * 4);
        mx = fmaxf(mx, fmaxf(fmaxf(v[i].x, v[i].y), fmaxf(v[i].z, v[i].w)));
    }
#pragma unroll
    for (int d2 = 1; d2 < 64; d2 <<= 1) mx = fmaxf(mx, __shfl_xor(mx, d2, 64));
    float sum = 0.f;
#pragma unroll
    for (int i = 0; i < 4; ++i) {
        v[i].x = __expf(v[i].x - mx);
        v[i].y = __expf(v[i].y - mx);
        v[i].z = __expf(v[i].z - mx);
        v[i].w = __expf(v[i].w - mx);
        sum += v[i].x + v[i].y + v[i].z + v[i].w;
    }
#pragma unroll
    for (int d2 = 1; d2 < 64; d2 <<= 1) sum += __shfl_xor(sum, d2, 64);
    float inv = 1.f / sum;
#pragma unroll
    for (int i = 0; i < 4; ++i) {
        v[i].x *= inv; v[i].y *= inv; v[i].z *= inv; v[i].w *= inv;
        *(float4*)(p + i * 256 + lane * 4) = v[i];
    }
}

extern "C" void kernel_launch(void* const* d_in, const int* in_sizes, int n_in,
                              void* d_out, int out_size, void* d_ws, size_t ws_size,
                              hipStream_t stream) {
    const float* query = (const float*)d_in[0];
    const float* key   = (const float*)d_in[1];
    const int*   mask  = (const int*)d_in[2];
    const float* Wq    = (const float*)d_in[3];
    const float* bq    = (const float*)d_in[4];
    const float* Wk    = (const float*)d_in[5];
    const float* bk    = (const float*)d_in[6];
    const float* wcomb = (const float*)d_in[7];
    const float* bcomb = (const float*)d_in[8];
    float* probs = (float*)d_out;                          // (B,S,S)
    float* ctx   = (float*)d_out + (size_t)BB * SS * SS;   // (B,H,S,DK) flat

    char* ws = (char*)d_ws;
    const size_t MB = 1ull << 20;
    ushort* query_hi = (ushort*)(ws);             // [0,8)
    ushort* query_lo = (ushort*)(ws + 8 * MB);    // [8,16)
    ushort* key_hi   = (ushort*)(ws + 16 * MB);   // [16,24)
    ushort* key_lo   = (ushort*)(ws + 24 * MB);   // [24,32)
    ushort* WqTh     = (ushort*)(ws + 32 * MB);   // [32,34)
    ushort* WqTl     = (ushort*)(ws + 34 * MB);   // [34,36)
    ushort* WkTh     = (ushort*)(ws + 36 * MB);   // [36,38)
    ushort* WkTl     = (ushort*)(ws + 38 * MB);   // [38,40)
    ushort* qw_bf    = (ushort*)(ws + 40 * MB);   // [40,48)
    ushort* q_hi     = (ushort*)(ws + 48 * MB);   // [48,56)
    ushort* q_lo     = (ushort*)(ws + 56 * MB);   // [56,64)
    u64*    mbits    = (u64*)(ws + 64 * MB);      // [64,64.5)
    ushort* kT       = (ushort*)(ws + 65 * MB);   // [65,73)
    // k outputs reuse the query staging region (dead after q-projection)
    ushort* k_hi     = (ushort*)(ws);             // [0,8)
    ushort* k_lo     = (ushort*)(ws + 8 * MB);    // [8,16)

    int nElem = BB * SS * DD;
    cvt_split<<<4096, 256, 0, stream>>>(query, query_hi, query_lo, nElem);
    cvt_split<<<4096, 256, 0, stream>>>(key, key_hi, key_lo, nElem);
    transposeW_split<<<dim3(16, 16, 2), 256, 0, stream>>>(Wq, Wk, WqTh, WqTl, WkTh, WkTl);
    pack_mask<<<16384, 256, 0, stream>>>(mask, mbits, BB * SS * (SS / 64));

    // q projection first (reads query_*), then k projection (overwrites query_* region)
    gemm_proj<0><<<dim3(8, 64), 256, 0, stream>>>(query_hi, query_lo, WqTh, WqTl,
                                                  bq, wcomb, q_hi, q_lo, qw_bf);
    gemm_proj<1><<<dim3(8, 64), 256, 0, stream>>>(key_hi, key_lo, WkTh, WkTl,
                                                  bk, nullptr, k_hi, k_lo, nullptr);

    transposeK<<<1024, 256, 0, stream>>>(k_hi, kT);

    attn_fused<<<dim3(16, 16, 4), 256, 0, stream>>>(q_hi, q_lo, k_hi, k_lo, kT, mbits, ctx);

    gemm_comb<<<dim3(8, 8, 4), 256, 0, stream>>>(qw_bf, k_hi, bcomb, probs);
    softmax_rows<<<1024, 256, 0, stream>>>(probs);
    (void)in_sizes; (void)n_in; (void)out_size; (void)ws_size;
}

// Round 9
// 251.301 us; speedup vs baseline: 1.8256x; 1.8256x over previous
//
#include <hip/hip_runtime.h>
#include <hip/hip_bf16.h>

#define BB 4
#define SS 1024
#define DD 1024
#define HH 16

typedef __attribute__((ext_vector_type(8))) short bf16x8;
typedef __attribute__((ext_vector_type(4))) float f32x4;
typedef unsigned int u32;
typedef unsigned long long u64;

__device__ __forceinline__ ushort f2bf(float f) {
    u32 u = __builtin_bit_cast(u32, f);
    u32 r = (u + 0x7fffu + ((u >> 16) & 1u)) >> 16;
    return (ushort)r;
}
__device__ __forceinline__ float bf2f(ushort h) {
    return __builtin_bit_cast(float, (u32)h << 16);
}

__device__ __forceinline__ void gload16(const ushort* g, ushort* l) {
    __builtin_amdgcn_global_load_lds(
        (const __attribute__((address_space(1))) u32*)(const void*)g,
        (__attribute__((address_space(3))) u32*)(void*)l, 16, 0, 0);
}

// ---------------- convert f32 -> bf16 hi + lo residual ----------------
__global__ __launch_bounds__(256) void cvt_split(const float* __restrict__ in,
                                                 ushort* __restrict__ hi,
                                                 ushort* __restrict__ lo, int n) {
    int i = (blockIdx.x * 256 + threadIdx.x) * 4;
    if (i < n) {
        float4 v = *(const float4*)(in + i);
        ushort4 h, l;
        float* pv = (float*)&v;
        ushort* ph = (ushort*)&h;
        ushort* pl = (ushort*)&l;
#pragma unroll
        for (int j = 0; j < 4; ++j) {
            ushort hh = f2bf(pv[j]);
            ph[j] = hh;
            pl[j] = f2bf(pv[j] - bf2f(hh));
        }
        *(ushort4*)(hi + i) = h;
        *(ushort4*)(lo + i) = l;
    }
}

// ---------------- transpose W (f32 DxD) -> bf16 W^T hi/lo ----------------
__global__ __launch_bounds__(256) void transposeW_split(
    const float* __restrict__ Wq, const float* __restrict__ Wk,
    ushort* __restrict__ WqTh, ushort* __restrict__ WqTl,
    ushort* __restrict__ WkTh, ushort* __restrict__ WkTl) {
    __shared__ float tile[64][65];
    const float* W = blockIdx.z ? Wk : Wq;
    ushort* WTh = blockIdx.z ? WkTh : WqTh;
    ushort* WTl = blockIdx.z ? WkTl : WqTl;
    int kb = blockIdx.y * 64, nb = blockIdx.x * 64;
    int tid = threadIdx.x;
    int tx = tid & 63, ty = tid >> 6;
#pragma unroll
    for (int i = 0; i < 16; ++i) {
        int kl = ty * 16 + i;
        tile[kl][tx] = W[(size_t)(kb + kl) * DD + nb + tx];
    }
    __syncthreads();
#pragma unroll
    for (int i = 0; i < 16; ++i) {
        int nl = ty * 16 + i;
        float v = tile[tx][nl];
        ushort hh = f2bf(v);
        size_t idx = (size_t)(nb + nl) * DD + kb + tx;
        WTh[idx] = hh;
        WTl[idx] = f2bf(v - bf2f(hh));
    }
}

// ---------------- pack mask to bits ----------------
__global__ __launch_bounds__(256) void pack_mask(const int* __restrict__ mask,
                                                 u64* __restrict__ bits, int nwords) {
    int gw = (int)((blockIdx.x * 256 + threadIdx.x) >> 6);
    int lane = threadIdx.x & 63;
    if (gw < nwords) {
        int v = mask[(size_t)gw * 64 + lane];
        u64 m = __ballot(v != 0);
        if (lane == 0) bits[gw] = m;
    }
}

// ---------------- transpose k_hi per head-tile into tiled kT ----------------
__global__ __launch_bounds__(256) void transposeK(const ushort* __restrict__ kh,
                                                  ushort* __restrict__ kT) {
    __shared__ ushort t[64 * 66];
    int blk = blockIdx.x;
    const ushort* src = kh + (size_t)blk * 4096;
    ushort* dst = kT + (size_t)blk * 4096;
    int tid = threadIdx.x;
#pragma unroll
    for (int i = 0; i < 2; ++i) {
        int c = tid + 256 * i;
        int r = c >> 3, col = (c & 7) << 3;
        uint4 v = *(const uint4*)(src + (size_t)c * 8);
        const uint* pv = (const uint*)&v;
        *(uint*)(t + r * 66 + col + 0) = pv[0];
        *(uint*)(t + r * 66 + col + 2) = pv[1];
        *(uint*)(t + r * 66 + col + 4) = pv[2];
        *(uint*)(t + r * 66 + col + 6) = pv[3];
    }
    __syncthreads();
#pragma unroll
    for (int i = 0; i < 2; ++i) {
        int c = tid + 256 * i;
        int d = c >> 3, k0 = (c & 7) << 3;
        uint4 o;
        ushort* po = (ushort*)&o;
#pragma unroll
        for (int j = 0; j < 8; ++j) po[j] = t[(k0 + j) * 66 + d];
        *(uint4*)(dst + d * 64 + k0) = o;
    }
}

// ---------------- split-precision projection GEMM, single K=1024 pass ----------------
// Stages Ah,Al (64x64) and Bh,Bl (128x64) per k-step; per fragment pair computes
// ah*bh + ah*bl + al*bh (48 MFMA/wave/k-step). LDS 48 KB. Epilogue as before.
template <int MODE>
__global__ __launch_bounds__(256) void gemm_proj(
    const ushort* __restrict__ Ah, const ushort* __restrict__ Al,
    const ushort* __restrict__ Bh, const ushort* __restrict__ Bl,
    const float* __restrict__ bias, const float* __restrict__ wcomb,
    ushort* __restrict__ Chi, ushort* __restrict__ Clo, ushort* __restrict__ Cw) {
    __shared__ __align__(16) ushort Ash[64 * 64];    // 8 KB
    __shared__ __align__(16) ushort Asl[64 * 64];    // 8 KB
    __shared__ __align__(16) ushort Bsh[128 * 64];   // 16 KB
    __shared__ __align__(16) ushort Bsl[128 * 64];   // 16 KB
    const int tn = blockIdx.x, tm = blockIdx.y;      // tn<8, tm<64
    const int tid = threadIdx.x, lane = tid & 63, w = tid >> 6;
    const int lr = lane >> 4, lc = lane & 15;
    f32x4 acc[8];
#pragma unroll
    for (int n = 0; n < 8; ++n) acc[n] = (f32x4){0.f, 0.f, 0.f, 0.f};

    for (int kt = 0; kt < DD; kt += 64) {
        __syncthreads();
#pragma unroll
        for (int i = 0; i < 2; ++i) {
            int c = tid + 256 * i;
            int r = c >> 3, col = (c & 7) << 3;
            size_t g = (size_t)(tm * 64 + r) * DD + kt + col;
            gload16(Ah + g, Ash + (w * 64 + 256 * i) * 8);
            gload16(Al + g, Asl + (w * 64 + 256 * i) * 8);
        }
#pragma unroll
        for (int i = 0; i < 4; ++i) {
            int c = tid + 256 * i;
            int r = c >> 3, col = (c & 7) << 3;
            size_t g = (size_t)(tn * 128 + r) * DD + kt + col;
            gload16(Bh + g, Bsh + (w * 64 + 256 * i) * 8);
            gload16(Bl + g, Bsl + (w * 64 + 256 * i) * 8);
        }
        __syncthreads();
#pragma unroll
        for (int t = 0; t < 2; ++t) {
            int aoff = (w * 16 + lc) * 64 + t * 32 + lr * 8;
            bf16x8 afh = *(const bf16x8*)(Ash + aoff);
            bf16x8 afl = *(const bf16x8*)(Asl + aoff);
#pragma unroll
            for (int n = 0; n < 8; ++n) {
                int boff = (n * 16 + lc) * 64 + t * 32 + lr * 8;
                bf16x8 bfh = *(const bf16x8*)(Bsh + boff);
                bf16x8 bfl = *(const bf16x8*)(Bsl + boff);
                acc[n] = __builtin_amdgcn_mfma_f32_16x16x32_bf16(afh, bfh, acc[n], 0, 0, 0);
                acc[n] = __builtin_amdgcn_mfma_f32_16x16x32_bf16(afh, bfl, acc[n], 0, 0, 0);
                acc[n] = __builtin_amdgcn_mfma_f32_16x16x32_bf16(afl, bfh, acc[n], 0, 0, 0);
            }
        }
    }
#pragma unroll
    for (int n = 0; n < 8; ++n) {
        int gcol = tn * 128 + n * 16 + lc;
#pragma unroll
        for (int r = 0; r < 4; ++r) {
            int grow = tm * 64 + w * 16 + lr * 4 + r;
            float v = acc[n][r] + bias[gcol];
            size_t idx = (size_t)grow * DD + gcol;
            ushort hh = f2bf(v);
            Chi[idx] = hh;
            Clo[idx] = f2bf(v - bf2f(hh));
            if (MODE == 0) Cw[idx] = f2bf(v * wcomb[(grow >> 6) & 15]);
        }
    }
}

// ---------------- combined-scores GEMM (head-block K) ----------------
__global__ __launch_bounds__(256) void gemm_comb(
    const ushort* __restrict__ Aq, const ushort* __restrict__ Bk,
    const float* __restrict__ bias, float* __restrict__ Cf) {
    __shared__ __align__(16) ushort As[128 * 64];
    __shared__ __align__(16) ushort Bs[128 * 64];
    const int bz = blockIdx.z;
    const ushort* Ab = Aq + (size_t)bz * SS * DD;
    const ushort* Bb = Bk + (size_t)bz * SS * DD;
    const int tn = blockIdx.x, tm = blockIdx.y;
    const int tid = threadIdx.x, lane = tid & 63, w = tid >> 6;
    const int wm = w >> 1, wn = w & 1;
    const int lr = lane >> 4, lc = lane & 15;
    f32x4 acc[4][4];
#pragma unroll
    for (int m = 0; m < 4; ++m)
#pragma unroll
        for (int n = 0; n < 4; ++n) acc[m][n] = (f32x4){0.f, 0.f, 0.f, 0.f};

    for (int h = 0; h < HH; ++h) {
        __syncthreads();
        const ushort* Asrc = Ab + (size_t)h * 65536 + tm * 8192;
        const ushort* Bsrc = Bb + (size_t)h * 65536 + tn * 8192;
#pragma unroll
        for (int i = 0; i < 4; ++i) {
            int c = tid + 256 * i;
            gload16(Asrc + (size_t)c * 8, As + (w * 64 + 256 * i) * 8);
        }
#pragma unroll
        for (int i = 0; i < 4; ++i) {
            int c = tid + 256 * i;
            gload16(Bsrc + (size_t)c * 8, Bs + (w * 64 + 256 * i) * 8);
        }
        __syncthreads();
        const ushort* Aw = As + (wm * 64) * 64;
        const ushort* Bw = Bs + (wn * 64) * 64;
#pragma unroll
        for (int t = 0; t < 2; ++t) {
            bf16x8 af[4], bfr[4];
#pragma unroll
            for (int m = 0; m < 4; ++m)
                af[m] = *(const bf16x8*)(Aw + (m * 16 + lc) * 64 + t * 32 + lr * 8);
#pragma unroll
            for (int n = 0; n < 4; ++n)
                bfr[n] = *(const bf16x8*)(Bw + (n * 16 + lc) * 64 + t * 32 + lr * 8);
#pragma unroll
            for (int m = 0; m < 4; ++m)
#pragma unroll
                for (int n = 0; n < 4; ++n)
                    acc[m][n] = __builtin_amdgcn_mfma_f32_16x16x32_bf16(af[m], bfr[n], acc[m][n], 0, 0, 0);
        }
    }
    float b0 = bias[0];
#pragma unroll
    for (int m = 0; m < 4; ++m) {
        int grow0 = tm * 128 + wm * 64 + m * 16 + lr * 4;
#pragma unroll
        for (int n = 0; n < 4; ++n) {
            int gcol = tn * 128 + wn * 64 + n * 16 + lc;
#pragma unroll
            for (int r = 0; r < 4; ++r)
                Cf[(size_t)bz * SS * SS + (size_t)(grow0 + r) * SS + gcol] = acc[m][n][r] + b0;
        }
    }
}

// swizzled LDS frag address (ushort units): row rr, 16B-block bi
#define SWZ(rr, bi) (((rr) << 6) + ((((bi) ^ ((rr) & 7))) << 3))

// ---------------- fused flash attention (V = K) — EXACT round-4 kernel ----------------
__global__ __launch_bounds__(256) void attn_fused(
    const ushort* __restrict__ qh_, const ushort* __restrict__ ql_,
    const ushort* __restrict__ kh_, const ushort* __restrict__ kl_,
    const ushort* __restrict__ kT_, const u64* __restrict__ mbits,
    float* __restrict__ ctx) {
    __shared__ __align__(16) ushort Kb[2][3][4096];  // [buf][kh,kl,kT]  48 KB
    __shared__ __align__(16) ushort Ps[4][16 * 68];  // 8.7 KB (total 57,856 B)
    const int qt = blockIdx.x, h = blockIdx.y, b = blockIdx.z;
    const int tid = threadIdx.x, lane = tid & 63, w = tid >> 6;
    const int lr = lane >> 4, lc = lane & 15;
    const int bh = b * HH + h;
    const size_t headbase = (size_t)bh * (SS * 64);

    // stage one K tile-set (kh, kl, kT); wave-uniform LDS chunk base, swizzled src
    auto stage = [&](int buf, int kt) {
#pragma unroll
        for (int i = 0; i < 2; ++i) {
            int ch = (w << 1) + i;                      // chunk 0..7 (1024B each)
            int row = (ch << 3) + (lane >> 3);          // 0..63
            int blkk = (lane & 7) ^ ((lane >> 3) & 7);  // swizzled 16B block
            size_t g = ((size_t)bh * 16 + kt) * 4096 + (size_t)row * 64 + blkk * 8;
            gload16(kh_ + g, &Kb[buf][0][ch * 512]);
            gload16(kl_ + g, &Kb[buf][1][ch * 512]);
            gload16(kT_ + g, &Kb[buf][2][ch * 512]);
        }
    };

    bf16x8 qfh[2], qfl[2];
    {
        size_t rowoff = headbase + (size_t)(qt * 64 + w * 16 + lc) * 64;
#pragma unroll
        for (int t = 0; t < 2; ++t) {
            qfh[t] = *(const bf16x8*)(qh_ + rowoff + t * 32 + lr * 8);
            qfl[t] = *(const bf16x8*)(ql_ + rowoff + t * 32 + lr * 8);
        }
    }
    f32x4 acc[4];
#pragma unroll
    for (int dt = 0; dt < 4; ++dt) acc[dt] = (f32x4){0.f, 0.f, 0.f, 0.f};
    float mrow[4] = {-3e38f, -3e38f, -3e38f, -3e38f};
    float lsum[4] = {0.f, 0.f, 0.f, 0.f};

    stage(0, 0);
    __syncthreads();
    int cur = 0;

    for (int kt = 0; kt < 16; ++kt) {
        if (kt < 15) stage(cur ^ 1, kt + 1);  // prefetch next (hidden under compute)

        const ushort* Bh = &Kb[cur][0][0];
        const ushort* Bl = &Kb[cur][1][0];
        const ushort* Vt = &Kb[cur][2][0];

        // QK^T (split precision): s = qh*kh + qh*kl + ql*kh
        f32x4 sc[4];
#pragma unroll
        for (int nt = 0; nt < 4; ++nt) {
            f32x4 z = (f32x4){0.f, 0.f, 0.f, 0.f};
            __builtin_amdgcn_s_setprio(1);
#pragma unroll
            for (int t = 0; t < 2; ++t) {
                bf16x8 kfh = *(const bf16x8*)(Bh + SWZ(nt * 16 + lc, t * 4 + lr));
                bf16x8 kfl = *(const bf16x8*)(Bl + SWZ(nt * 16 + lc, t * 4 + lr));
                z = __builtin_amdgcn_mfma_f32_16x16x32_bf16(qfh[t], kfh, z, 0, 0, 0);
                z = __builtin_amdgcn_mfma_f32_16x16x32_bf16(qfh[t], kfl, z, 0, 0, 0);
                z = __builtin_amdgcn_mfma_f32_16x16x32_bf16(qfl[t], kfh, z, 0, 0, 0);
            }
            __builtin_amdgcn_s_setprio(0);
            sc[nt] = z;
        }

        // mask + online softmax (row lr*4+r lives in a contiguous 16-lane group)
#pragma unroll
        for (int r = 0; r < 4; ++r) {
            u64 wbit = mbits[((size_t)b * SS + qt * 64 + w * 16 + lr * 4 + r) * 16 + kt];
            float rmax = -3e38f;
#pragma unroll
            for (int nt = 0; nt < 4; ++nt) {
                int kkloc = nt * 16 + lc;
                float v = sc[nt][r];
                v = ((wbit >> kkloc) & 1ULL) ? v : -3e38f;
                sc[nt][r] = v;
                rmax = fmaxf(rmax, v);
            }
#pragma unroll
            for (int d2 = 1; d2 < 16; d2 <<= 1) rmax = fmaxf(rmax, __shfl_xor(rmax, d2, 64));
            float mnew = fmaxf(mrow[r], rmax);
            float scale = __expf(mrow[r] - mnew);
            float rsum = 0.f;
#pragma unroll
            for (int nt = 0; nt < 4; ++nt) {
                float p = __expf(sc[nt][r] - mnew);
                sc[nt][r] = p;
                rsum += p;
            }
#pragma unroll
            for (int d2 = 1; d2 < 16; d2 <<= 1) rsum += __shfl_xor(rsum, d2, 64);
            lsum[r] = lsum[r] * scale + rsum;
            mrow[r] = mnew;
#pragma unroll
            for (int dt = 0; dt < 4; ++dt) acc[dt][r] *= scale;
        }

        // P -> per-wave LDS (C/D layout -> A-frag layout), pitch 68
        ushort* P = &Ps[w][0];
#pragma unroll
        for (int nt = 0; nt < 4; ++nt)
#pragma unroll
            for (int r = 0; r < 4; ++r)
                P[(lr * 4 + r) * 68 + nt * 16 + lc] = f2bf(sc[nt][r]);
        asm volatile("s_waitcnt lgkmcnt(0)" ::: "memory");
        __builtin_amdgcn_sched_barrier(0);

        bf16x8 pf[2];
#pragma unroll
        for (int t = 0; t < 2; ++t)
            pf[t] = *(const bf16x8*)(P + lc * 68 + t * 32 + lr * 8);

        // PV: context += P @ K_tile (V = K hi, from pre-transposed kT)
        __builtin_amdgcn_s_setprio(1);
#pragma unroll
        for (int dt = 0; dt < 4; ++dt) {
#pragma unroll
            for (int t = 0; t < 2; ++t) {
                bf16x8 vf = *(const bf16x8*)(Vt + SWZ(dt * 16 + lc, t * 4 + lr));
                acc[dt] = __builtin_amdgcn_mfma_f32_16x16x32_bf16(pf[t], vf, acc[dt], 0, 0, 0);
            }
        }
        __builtin_amdgcn_s_setprio(0);

        if (kt < 15) __syncthreads();  // drains vmcnt (stage) + syncs buffers
        cur ^= 1;
    }
    // epilogue: output context layout is (B, H, S, DK) contiguous (reference reshape)
#pragma unroll
    for (int r = 0; r < 4; ++r) {
        float l = lsum[r];
        float inv = (l > 0.f) ? 1.f / l : 0.f;
        int q = qt * 64 + w * 16 + lr * 4 + r;
#pragma unroll
        for (int dt = 0; dt < 4; ++dt)
            ctx[(((size_t)bh) * SS + q) * 64 + dt * 16 + lc] = acc[dt][r] * inv;
    }
}

// ---------------- row softmax for probs ----------------
__global__ __launch_bounds__(256) void softmax_rows(float* __restrict__ data) {
    int w = threadIdx.x >> 6, lane = threadIdx.x & 63;
    float* p = data + ((size_t)blockIdx.x * 4 + w) * SS;
    float4 v[4];
    float mx = -3e38f;
#pragma unroll
    for (int i = 0; i < 4; ++i) {
        v[i] = *(const float4*)(p + i * 256 + lane * 4);
        mx = fmaxf(mx, fmaxf(fmaxf(v[i].x, v[i].y), fmaxf(v[i].z, v[i].w)));
    }
#pragma unroll
    for (int d2 = 1; d2 < 64; d2 <<= 1) mx = fmaxf(mx, __shfl_xor(mx, d2, 64));
    float sum = 0.f;
#pragma unroll
    for (int i = 0; i < 4; ++i) {
        v[i].x = __expf(v[i].x - mx);
        v[i].y = __expf(v[i].y - mx);
        v[i].z = __expf(v[i].z - mx);
        v[i].w = __expf(v[i].w - mx);
        sum += v[i].x + v[i].y + v[i].z + v[i].w;
    }
#pragma unroll
    for (int d2 = 1; d2 < 64; d2 <<= 1) sum += __shfl_xor(sum, d2, 64);
    float inv = 1.f / sum;
#pragma unroll
    for (int i = 0; i < 4; ++i) {
        v[i].x *= inv; v[i].y *= inv; v[i].z *= inv; v[i].w *= inv;
        *(float4*)(p + i * 256 + lane * 4) = v[i];
    }
}

extern "C" void kernel_launch(void* const* d_in, const int* in_sizes, int n_in,
                              void* d_out, int out_size, void* d_ws, size_t ws_size,
                              hipStream_t stream) {
    const float* query = (const float*)d_in[0];
    const float* key   = (const float*)d_in[1];
    const int*   mask  = (const int*)d_in[2];
    const float* Wq    = (const float*)d_in[3];
    const float* bq    = (const float*)d_in[4];
    const float* Wk    = (const float*)d_in[5];
    const float* bk    = (const float*)d_in[6];
    const float* wcomb = (const float*)d_in[7];
    const float* bcomb = (const float*)d_in[8];
    float* probs = (float*)d_out;                          // (B,S,S)
    float* ctx   = (float*)d_out + (size_t)BB * SS * SS;   // (B,H,S,DK) flat

    char* ws = (char*)d_ws;
    const size_t MB = 1ull << 20;
    ushort* query_hi = (ushort*)(ws);             // [0,8)
    ushort* query_lo = (ushort*)(ws + 8 * MB);    // [8,16)
    ushort* key_hi   = (ushort*)(ws + 16 * MB);   // [16,24)
    ushort* key_lo   = (ushort*)(ws + 24 * MB);   // [24,32)
    ushort* WqTh     = (ushort*)(ws + 32 * MB);   // [32,34)
    ushort* WqTl     = (ushort*)(ws + 34 * MB);   // [34,36)
    ushort* WkTh     = (ushort*)(ws + 36 * MB);   // [36,38)
    ushort* WkTl     = (ushort*)(ws + 38 * MB);   // [38,40)
    ushort* qw_bf    = (ushort*)(ws + 40 * MB);   // [40,48)
    ushort* q_hi     = (ushort*)(ws + 48 * MB);   // [48,56)
    ushort* q_lo     = (ushort*)(ws + 56 * MB);   // [56,64)
    u64*    mbits    = (u64*)(ws + 64 * MB);      // [64,64.5)
    ushort* kT       = (ushort*)(ws + 65 * MB);   // [65,73)
    // k outputs reuse the query staging region (dead after q-projection)
    ushort* k_hi     = (ushort*)(ws);             // [0,8)
    ushort* k_lo     = (ushort*)(ws + 8 * MB);    // [8,16)

    int nElem = BB * SS * DD;
    cvt_split<<<4096, 256, 0, stream>>>(query, query_hi, query_lo, nElem);
    cvt_split<<<4096, 256, 0, stream>>>(key, key_hi, key_lo, nElem);
    transposeW_split<<<dim3(16, 16, 2), 256, 0, stream>>>(Wq, Wk, WqTh, WqTl, WkTh, WkTl);
    pack_mask<<<16384, 256, 0, stream>>>(mask, mbits, BB * SS * (SS / 64));

    // q projection first (reads query_*), then k projection (overwrites query_* region)
    gemm_proj<0><<<dim3(8, 64), 256, 0, stream>>>(query_hi, query_lo, WqTh, WqTl,
                                                  bq, wcomb, q_hi, q_lo, qw_bf);
    gemm_proj<1><<<dim3(8, 64), 256, 0, stream>>>(key_hi, key_lo, WkTh, WkTl,
                                                  bk, nullptr, k_hi, k_lo, nullptr);

    transposeK<<<1024, 256, 0, stream>>>(k_hi, kT);

    attn_fused<<<dim3(16, 16, 4), 256, 0, stream>>>(q_hi, q_lo, k_hi, k_lo, kT, mbits, ctx);

    gemm_comb<<<dim3(8, 8, 4), 256, 0, stream>>>(qw_bf, k_hi, bcomb, probs);
    softmax_rows<<<1024, 256, 0, stream>>>(probs);
    (void)in_sizes; (void)n_in; (void)out_size; (void)ws_size;
}

// Round 10
// 238.040 us; speedup vs baseline: 1.9273x; 1.0557x over previous
//
#include <hip/hip_runtime.h>
#include <hip/hip_bf16.h>

#define BB 4
#define SS 1024
#define DD 1024
#define HH 16

typedef __attribute__((ext_vector_type(8))) short bf16x8;
typedef __attribute__((ext_vector_type(4))) float f32x4;
typedef unsigned int u32;
typedef unsigned long long u64;

__device__ __forceinline__ ushort f2bf(float f) {
    u32 u = __builtin_bit_cast(u32, f);
    u32 r = (u + 0x7fffu + ((u >> 16) & 1u)) >> 16;
    return (ushort)r;
}
__device__ __forceinline__ float bf2f(ushort h) {
    return __builtin_bit_cast(float, (u32)h << 16);
}

__device__ __forceinline__ void gload16(const ushort* g, ushort* l) {
    __builtin_amdgcn_global_load_lds(
        (const __attribute__((address_space(1))) u32*)(const void*)g,
        (__attribute__((address_space(3))) u32*)(void*)l, 16, 0, 0);
}

// ---------------- convert f32 -> bf16 hi + lo residual (q and k fused) ----------------
__global__ __launch_bounds__(256) void cvt_split2(
    const float* __restrict__ q, const float* __restrict__ k,
    ushort* __restrict__ qh, ushort* __restrict__ ql,
    ushort* __restrict__ kh, ushort* __restrict__ kl) {
    int bid = blockIdx.x;
    const float* in;
    ushort *hi, *lo;
    if (bid < 4096) { in = q; hi = qh; lo = ql; }
    else            { in = k; hi = kh; lo = kl; bid -= 4096; }
    int i = (bid * 256 + threadIdx.x) * 4;
    float4 v = *(const float4*)(in + i);
    ushort4 h, l;
    float* pv = (float*)&v;
    ushort* ph = (ushort*)&h;
    ushort* pl = (ushort*)&l;
#pragma unroll
    for (int j = 0; j < 4; ++j) {
        ushort hh = f2bf(pv[j]);
        ph[j] = hh;
        pl[j] = f2bf(pv[j] - bf2f(hh));
    }
    *(ushort4*)(hi + i) = h;
    *(ushort4*)(lo + i) = l;
}

// ---------------- transpose W (f32 DxD) -> bf16 W^T hi/lo ----------------
__global__ __launch_bounds__(256) void transposeW_split(
    const float* __restrict__ Wq, const float* __restrict__ Wk,
    ushort* __restrict__ WqTh, ushort* __restrict__ WqTl,
    ushort* __restrict__ WkTh, ushort* __restrict__ WkTl) {
    __shared__ float tile[64][65];
    const float* W = blockIdx.z ? Wk : Wq;
    ushort* WTh = blockIdx.z ? WkTh : WqTh;
    ushort* WTl = blockIdx.z ? WkTl : WqTl;
    int kb = blockIdx.y * 64, nb = blockIdx.x * 64;
    int tid = threadIdx.x;
    int tx = tid & 63, ty = tid >> 6;
#pragma unroll
    for (int i = 0; i < 16; ++i) {
        int kl = ty * 16 + i;
        tile[kl][tx] = W[(size_t)(kb + kl) * DD + nb + tx];
    }
    __syncthreads();
#pragma unroll
    for (int i = 0; i < 16; ++i) {
        int nl = ty * 16 + i;
        float v = tile[tx][nl];
        ushort hh = f2bf(v);
        size_t idx = (size_t)(nb + nl) * DD + kb + tx;
        WTh[idx] = hh;
        WTl[idx] = f2bf(v - bf2f(hh));
    }
}

// ---------------- pack mask to bits ----------------
__global__ __launch_bounds__(256) void pack_mask(const int* __restrict__ mask,
                                                 u64* __restrict__ bits, int nwords) {
    int gw = (int)((blockIdx.x * 256 + threadIdx.x) >> 6);
    int lane = threadIdx.x & 63;
    if (gw < nwords) {
        int v = mask[(size_t)gw * 64 + lane];
        u64 m = __ballot(v != 0);
        if (lane == 0) bits[gw] = m;
    }
}

// ---------------- transpose k_hi per head-tile into tiled kT ----------------
__global__ __launch_bounds__(256) void transposeK(const ushort* __restrict__ kh,
                                                  ushort* __restrict__ kT) {
    __shared__ ushort t[64 * 66];
    int blk = blockIdx.x;
    const ushort* src = kh + (size_t)blk * 4096;
    ushort* dst = kT + (size_t)blk * 4096;
    int tid = threadIdx.x;
#pragma unroll
    for (int i = 0; i < 2; ++i) {
        int c = tid + 256 * i;
        int r = c >> 3, col = (c & 7) << 3;
        uint4 v = *(const uint4*)(src + (size_t)c * 8);
        const uint* pv = (const uint*)&v;
        *(uint*)(t + r * 66 + col + 0) = pv[0];
        *(uint*)(t + r * 66 + col + 2) = pv[1];
        *(uint*)(t + r * 66 + col + 4) = pv[2];
        *(uint*)(t + r * 66 + col + 6) = pv[3];
    }
    __syncthreads();
#pragma unroll
    for (int i = 0; i < 2; ++i) {
        int c = tid + 256 * i;
        int d = c >> 3, k0 = (c & 7) << 3;
        uint4 o;
        ushort* po = (ushort*)&o;
#pragma unroll
        for (int j = 0; j < 8; ++j) po[j] = t[(k0 + j) * 66 + d];
        *(uint4*)(dst + d * 64 + k0) = o;
    }
}

// ---------------- split-precision projection GEMM, q & k fused via blockIdx.z ----------
// mode 0: query projection (writes Cq_hi/Cq_lo/Cw); mode 1: key projection (Ck_hi/Ck_lo).
__global__ __launch_bounds__(256) void gemm_proj_f(
    const ushort* __restrict__ Aq_h, const ushort* __restrict__ Aq_l,
    const ushort* __restrict__ Ak_h, const ushort* __restrict__ Ak_l,
    const ushort* __restrict__ Bq_h, const ushort* __restrict__ Bq_l,
    const ushort* __restrict__ Bk_h, const ushort* __restrict__ Bk_l,
    const float* __restrict__ bq, const float* __restrict__ bk,
    const float* __restrict__ wcomb,
    ushort* __restrict__ Cq_hi, ushort* __restrict__ Cq_lo, ushort* __restrict__ Cw,
    ushort* __restrict__ Ck_hi, ushort* __restrict__ Ck_lo, int mode_base) {
    __shared__ __align__(16) ushort Ash[64 * 64];
    __shared__ __align__(16) ushort Asl[64 * 64];
    __shared__ __align__(16) ushort Bsh[128 * 64];
    __shared__ __align__(16) ushort Bsl[128 * 64];
    const int mode = blockIdx.z + mode_base;
    const ushort* Ah = mode ? Ak_h : Aq_h;
    const ushort* Al = mode ? Ak_l : Aq_l;
    const ushort* Bh = mode ? Bk_h : Bq_h;
    const ushort* Bl = mode ? Bk_l : Bq_l;
    const float* bias = mode ? bk : bq;
    ushort* Chi = mode ? Ck_hi : Cq_hi;
    ushort* Clo = mode ? Ck_lo : Cq_lo;
    const int tn = blockIdx.x, tm = blockIdx.y;
    const int tid = threadIdx.x, lane = tid & 63, w = tid >> 6;
    const int lr = lane >> 4, lc = lane & 15;
    f32x4 acc[8];
#pragma unroll
    for (int n = 0; n < 8; ++n) acc[n] = (f32x4){0.f, 0.f, 0.f, 0.f};

    for (int kt = 0; kt < DD; kt += 64) {
        __syncthreads();
#pragma unroll
        for (int i = 0; i < 2; ++i) {
            int c = tid + 256 * i;
            int r = c >> 3, col = (c & 7) << 3;
            size_t g = (size_t)(tm * 64 + r) * DD + kt + col;
            gload16(Ah + g, Ash + (w * 64 + 256 * i) * 8);
            gload16(Al + g, Asl + (w * 64 + 256 * i) * 8);
        }
#pragma unroll
        for (int i = 0; i < 4; ++i) {
            int c = tid + 256 * i;
            int r = c >> 3, col = (c & 7) << 3;
            size_t g = (size_t)(tn * 128 + r) * DD + kt + col;
            gload16(Bh + g, Bsh + (w * 64 + 256 * i) * 8);
            gload16(Bl + g, Bsl + (w * 64 + 256 * i) * 8);
        }
        __syncthreads();
#pragma unroll
        for (int t = 0; t < 2; ++t) {
            int aoff = (w * 16 + lc) * 64 + t * 32 + lr * 8;
            bf16x8 afh = *(const bf16x8*)(Ash + aoff);
            bf16x8 afl = *(const bf16x8*)(Asl + aoff);
#pragma unroll
            for (int n = 0; n < 8; ++n) {
                int boff = (n * 16 + lc) * 64 + t * 32 + lr * 8;
                bf16x8 bfh = *(const bf16x8*)(Bsh + boff);
                bf16x8 bfl = *(const bf16x8*)(Bsl + boff);
                acc[n] = __builtin_amdgcn_mfma_f32_16x16x32_bf16(afh, bfh, acc[n], 0, 0, 0);
                acc[n] = __builtin_amdgcn_mfma_f32_16x16x32_bf16(afh, bfl, acc[n], 0, 0, 0);
                acc[n] = __builtin_amdgcn_mfma_f32_16x16x32_bf16(afl, bfh, acc[n], 0, 0, 0);
            }
        }
    }
#pragma unroll
    for (int n = 0; n < 8; ++n) {
        int gcol = tn * 128 + n * 16 + lc;
#pragma unroll
        for (int r = 0; r < 4; ++r) {
            int grow = tm * 64 + w * 16 + lr * 4 + r;
            float v = acc[n][r] + bias[gcol];
            size_t idx = (size_t)grow * DD + gcol;
            ushort hh = f2bf(v);
            Chi[idx] = hh;
            Clo[idx] = f2bf(v - bf2f(hh));
            if (mode == 0) Cw[idx] = f2bf(v * wcomb[(grow >> 6) & 15]);
        }
    }
}

// swizzled LDS frag address (ushort units): row rr, 16B-block bi
#define SWZ(rr, bi) (((rr) << 6) + ((((bi) ^ ((rr) & 7))) << 3))

// ---------------- FAT kernel: gemm_comb (blocks 0..255) || attn (blocks 256..1279) ----
// attn body is byte-identical to the round-9-proven kernel; comb body to gemm_comb.
// Shared pool 57,856 B aliased by both paths.
__global__ __launch_bounds__(256) void attn_comb(
    const ushort* __restrict__ qh_, const ushort* __restrict__ ql_,
    const ushort* __restrict__ kh_, const ushort* __restrict__ kl_,
    const ushort* __restrict__ kT_, const u64* __restrict__ mbits,
    float* __restrict__ ctx,
    const ushort* __restrict__ Aq, const ushort* __restrict__ Bk,
    const float* __restrict__ bcomb, float* __restrict__ probs) {
    __shared__ __align__(16) ushort shm[28928];  // 57,856 B
    const int bid = blockIdx.x;
    const int tid = threadIdx.x, lane = tid & 63, w = tid >> 6;
    const int lr = lane >> 4, lc = lane & 15;

    if (bid < 256) {
        // ---------------- combined-scores GEMM ----------------
        ushort* As = shm;           // 128*64
        ushort* Bs = shm + 8192;    // 128*64
        const int tn = bid & 7, tm = (bid >> 3) & 7, bz = bid >> 6;
        const ushort* Ab = Aq + (size_t)bz * SS * DD;
        const ushort* Bb = Bk + (size_t)bz * SS * DD;
        const int wm = w >> 1, wn = w & 1;
        f32x4 acc[4][4];
#pragma unroll
        for (int m = 0; m < 4; ++m)
#pragma unroll
            for (int n = 0; n < 4; ++n) acc[m][n] = (f32x4){0.f, 0.f, 0.f, 0.f};

        for (int h = 0; h < HH; ++h) {
            __syncthreads();
            const ushort* Asrc = Ab + (size_t)h * 65536 + tm * 8192;
            const ushort* Bsrc = Bb + (size_t)h * 65536 + tn * 8192;
#pragma unroll
            for (int i = 0; i < 4; ++i) {
                int c = tid + 256 * i;
                gload16(Asrc + (size_t)c * 8, As + (w * 64 + 256 * i) * 8);
            }
#pragma unroll
            for (int i = 0; i < 4; ++i) {
                int c = tid + 256 * i;
                gload16(Bsrc + (size_t)c * 8, Bs + (w * 64 + 256 * i) * 8);
            }
            __syncthreads();
            const ushort* Aw = As + (wm * 64) * 64;
            const ushort* Bw = Bs + (wn * 64) * 64;
#pragma unroll
            for (int t = 0; t < 2; ++t) {
                bf16x8 af[4], bfr[4];
#pragma unroll
                for (int m = 0; m < 4; ++m)
                    af[m] = *(const bf16x8*)(Aw + (m * 16 + lc) * 64 + t * 32 + lr * 8);
#pragma unroll
                for (int n = 0; n < 4; ++n)
                    bfr[n] = *(const bf16x8*)(Bw + (n * 16 + lc) * 64 + t * 32 + lr * 8);
#pragma unroll
                for (int m = 0; m < 4; ++m)
#pragma unroll
                    for (int n = 0; n < 4; ++n)
                        acc[m][n] = __builtin_amdgcn_mfma_f32_16x16x32_bf16(af[m], bfr[n], acc[m][n], 0, 0, 0);
            }
        }
        float b0 = bcomb[0];
#pragma unroll
        for (int m = 0; m < 4; ++m) {
            int grow0 = tm * 128 + wm * 64 + m * 16 + lr * 4;
#pragma unroll
            for (int n = 0; n < 4; ++n) {
                int gcol = tn * 128 + wn * 64 + n * 16 + lc;
#pragma unroll
                for (int r = 0; r < 4; ++r)
                    probs[(size_t)bz * SS * SS + (size_t)(grow0 + r) * SS + gcol] = acc[m][n][r] + b0;
            }
        }
        return;
    }

    // ---------------- flash attention (V = K), round-9-proven body ----------------
    const int abid = bid - 256;
    const int qt = abid & 15, h = (abid >> 4) & 15, b = abid >> 8;
    ushort* KbBase = shm;          // [2][3][4096]
    ushort* PsBase = shm + 24576;  // [4][16*68]
    const int bh = b * HH + h;
    const size_t headbase = (size_t)bh * (SS * 64);

    auto KB = [&](int buf, int j) -> ushort* { return KbBase + (buf * 3 + j) * 4096; };
    auto stage = [&](int buf, int kt) {
#pragma unroll
        for (int i = 0; i < 2; ++i) {
            int ch = (w << 1) + i;                      // chunk 0..7 (1024B each)
            int row = (ch << 3) + (lane >> 3);          // 0..63
            int blkk = (lane & 7) ^ ((lane >> 3) & 7);  // swizzled 16B block
            size_t g = ((size_t)bh * 16 + kt) * 4096 + (size_t)row * 64 + blkk * 8;
            gload16(kh_ + g, KB(buf, 0) + ch * 512);
            gload16(kl_ + g, KB(buf, 1) + ch * 512);
            gload16(kT_ + g, KB(buf, 2) + ch * 512);
        }
    };

    bf16x8 qfh[2], qfl[2];
    {
        size_t rowoff = headbase + (size_t)(qt * 64 + w * 16 + lc) * 64;
#pragma unroll
        for (int t = 0; t < 2; ++t) {
            qfh[t] = *(const bf16x8*)(qh_ + rowoff + t * 32 + lr * 8);
            qfl[t] = *(const bf16x8*)(ql_ + rowoff + t * 32 + lr * 8);
        }
    }
    f32x4 acc[4];
#pragma unroll
    for (int dt = 0; dt < 4; ++dt) acc[dt] = (f32x4){0.f, 0.f, 0.f, 0.f};
    float mrow[4] = {-3e38f, -3e38f, -3e38f, -3e38f};
    float lsum[4] = {0.f, 0.f, 0.f, 0.f};

    stage(0, 0);
    __syncthreads();
    int cur = 0;

    for (int kt = 0; kt < 16; ++kt) {
        if (kt < 15) stage(cur ^ 1, kt + 1);  // prefetch next (hidden under compute)

        const ushort* Bh = KB(cur, 0);
        const ushort* Bl = KB(cur, 1);
        const ushort* Vt = KB(cur, 2);

        // QK^T (split precision): s = qh*kh + qh*kl + ql*kh
        f32x4 sc[4];
#pragma unroll
        for (int nt = 0; nt < 4; ++nt) {
            f32x4 z = (f32x4){0.f, 0.f, 0.f, 0.f};
            __builtin_amdgcn_s_setprio(1);
#pragma unroll
            for (int t = 0; t < 2; ++t) {
                bf16x8 kfh = *(const bf16x8*)(Bh + SWZ(nt * 16 + lc, t * 4 + lr));
                bf16x8 kfl = *(const bf16x8*)(Bl + SWZ(nt * 16 + lc, t * 4 + lr));
                z = __builtin_amdgcn_mfma_f32_16x16x32_bf16(qfh[t], kfh, z, 0, 0, 0);
                z = __builtin_amdgcn_mfma_f32_16x16x32_bf16(qfh[t], kfl, z, 0, 0, 0);
                z = __builtin_amdgcn_mfma_f32_16x16x32_bf16(qfl[t], kfh, z, 0, 0, 0);
            }
            __builtin_amdgcn_s_setprio(0);
            sc[nt] = z;
        }

        // mask + online softmax (row lr*4+r lives in a contiguous 16-lane group)
#pragma unroll
        for (int r = 0; r < 4; ++r) {
            u64 wbit = mbits[((size_t)b * SS + qt * 64 + w * 16 + lr * 4 + r) * 16 + kt];
            float rmax = -3e38f;
#pragma unroll
            for (int nt = 0; nt < 4; ++nt) {
                int kkloc = nt * 16 + lc;
                float v = sc[nt][r];
                v = ((wbit >> kkloc) & 1ULL) ? v : -3e38f;
                sc[nt][r] = v;
                rmax = fmaxf(rmax, v);
            }
#pragma unroll
            for (int d2 = 1; d2 < 16; d2 <<= 1) rmax = fmaxf(rmax, __shfl_xor(rmax, d2, 64));
            float mnew = fmaxf(mrow[r], rmax);
            float scale = __expf(mrow[r] - mnew);
            float rsum = 0.f;
#pragma unroll
            for (int nt = 0; nt < 4; ++nt) {
                float p = __expf(sc[nt][r] - mnew);
                sc[nt][r] = p;
                rsum += p;
            }
#pragma unroll
            for (int d2 = 1; d2 < 16; d2 <<= 1) rsum += __shfl_xor(rsum, d2, 64);
            lsum[r] = lsum[r] * scale + rsum;
            mrow[r] = mnew;
#pragma unroll
            for (int dt = 0; dt < 4; ++dt) acc[dt][r] *= scale;
        }

        // P -> per-wave LDS (C/D layout -> A-frag layout), pitch 68
        ushort* P = PsBase + w * 1088;
#pragma unroll
        for (int nt = 0; nt < 4; ++nt)
#pragma unroll
            for (int r = 0; r < 4; ++r)
                P[(lr * 4 + r) * 68 + nt * 16 + lc] = f2bf(sc[nt][r]);
        asm volatile("s_waitcnt lgkmcnt(0)" ::: "memory");
        __builtin_amdgcn_sched_barrier(0);

        bf16x8 pf[2];
#pragma unroll
        for (int t = 0; t < 2; ++t)
            pf[t] = *(const bf16x8*)(P + lc * 68 + t * 32 + lr * 8);

        // PV: context += P @ K_tile (V = K hi, from pre-transposed kT)
        __builtin_amdgcn_s_setprio(1);
#pragma unroll
        for (int dt = 0; dt < 4; ++dt) {
#pragma unroll
            for (int t = 0; t < 2; ++t) {
                bf16x8 vf = *(const bf16x8*)(Vt + SWZ(dt * 16 + lc, t * 4 + lr));
                acc[dt] = __builtin_amdgcn_mfma_f32_16x16x32_bf16(pf[t], vf, acc[dt], 0, 0, 0);
            }
        }
        __builtin_amdgcn_s_setprio(0);

        if (kt < 15) __syncthreads();  // drains vmcnt (stage) + syncs buffers
        cur ^= 1;
    }
    // epilogue: output context layout is (B, H, S, DK) contiguous (reference reshape)
#pragma unroll
    for (int r = 0; r < 4; ++r) {
        float l = lsum[r];
        float inv = (l > 0.f) ? 1.f / l : 0.f;
        int q = qt * 64 + w * 16 + lr * 4 + r;
#pragma unroll
        for (int dt = 0; dt < 4; ++dt)
            ctx[(((size_t)bh) * SS + q) * 64 + dt * 16 + lc] = acc[dt][r] * inv;
    }
}

// ---------------- row softmax for probs ----------------
__global__ __launch_bounds__(256) void softmax_rows(float* __restrict__ data) {
    int w = threadIdx.x >> 6, lane = threadIdx.x & 63;
    float* p = data + ((size_t)blockIdx.x * 4 + w) * SS;
    float4 v[4];
    float mx = -3e38f;
#pragma unroll
    for (int i = 0; i < 4; ++i) {
        v[i] = *(const float4*)(p + i * 256 + lane * 4);
        mx = fmaxf(mx, fmaxf(fmaxf(v[i].x, v[i].y), fmaxf(v[i].z, v[i].w)));
    }
#pragma unroll
    for (int d2 = 1; d2 < 64; d2 <<= 1) mx = fmaxf(mx, __shfl_xor(mx, d2, 64));
    float sum = 0.f;
#pragma unroll
    for (int i = 0; i < 4; ++i) {
        v[i].x = __expf(v[i].x - mx);
        v[i].y = __expf(v[i].y - mx);
        v[i].z = __expf(v[i].z - mx);
        v[i].w = __expf(v[i].w - mx);
        sum += v[i].x + v[i].y + v[i].z + v[i].w;
    }
#pragma unroll
    for (int d2 = 1; d2 < 64; d2 <<= 1) sum += __shfl_xor(sum, d2, 64);
    float inv = 1.f / sum;
#pragma unroll
    for (int i = 0; i < 4; ++i) {
        v[i].x *= inv; v[i].y *= inv; v[i].z *= inv; v[i].w *= inv;
        *(float4*)(p + i * 256 + lane * 4) = v[i];
    }
}

extern "C" void kernel_launch(void* const* d_in, const int* in_sizes, int n_in,
                              void* d_out, int out_size, void* d_ws, size_t ws_size,
                              hipStream_t stream) {
    const float* query = (const float*)d_in[0];
    const float* key   = (const float*)d_in[1];
    const int*   mask  = (const int*)d_in[2];
    const float* Wq    = (const float*)d_in[3];
    const float* bq    = (const float*)d_in[4];
    const float* Wk    = (const float*)d_in[5];
    const float* bk    = (const float*)d_in[6];
    const float* wcomb = (const float*)d_in[7];
    const float* bcomb = (const float*)d_in[8];
    float* probs = (float*)d_out;                          // (B,S,S)
    float* ctx   = (float*)d_out + (size_t)BB * SS * SS;   // (B,H,S,DK) flat

    char* ws = (char*)d_ws;
    const size_t MB = 1ull << 20;
    ushort* query_hi = (ushort*)(ws);             // [0,8)
    ushort* query_lo = (ushort*)(ws + 8 * MB);    // [8,16)
    ushort* key_hi   = (ushort*)(ws + 16 * MB);   // [16,24)
    ushort* key_lo   = (ushort*)(ws + 24 * MB);   // [24,32)
    ushort* WqTh     = (ushort*)(ws + 32 * MB);   // [32,34)
    ushort* WqTl     = (ushort*)(ws + 34 * MB);   // [34,36)
    ushort* WkTh     = (ushort*)(ws + 36 * MB);   // [36,38)
    ushort* WkTl     = (ushort*)(ws + 38 * MB);   // [38,40)
    ushort* qw_bf    = (ushort*)(ws + 40 * MB);   // [40,48)
    ushort* q_hi     = (ushort*)(ws + 48 * MB);   // [48,56)
    ushort* q_lo     = (ushort*)(ws + 56 * MB);   // [56,64)
    u64*    mbits    = (u64*)(ws + 64 * MB);      // [64,64.5)
    ushort* kT       = (ushort*)(ws + 65 * MB);   // [65,73)

    // Concurrent q/k projections need k outputs off the query-overlay region.
    const bool bigws = ws_size >= 90 * MB;
    ushort* k_hi = bigws ? (ushort*)(ws + 73 * MB) : (ushort*)(ws);
    ushort* k_lo = bigws ? (ushort*)(ws + 81 * MB) : (ushort*)(ws + 8 * MB);

    cvt_split2<<<8192, 256, 0, stream>>>(query, key, query_hi, query_lo, key_hi, key_lo);
    transposeW_split<<<dim3(16, 16, 2), 256, 0, stream>>>(Wq, Wk, WqTh, WqTl, WkTh, WkTl);
    pack_mask<<<16384, 256, 0, stream>>>(mask, mbits, BB * SS * (SS / 64));

    if (bigws) {
        gemm_proj_f<<<dim3(8, 64, 2), 256, 0, stream>>>(
            query_hi, query_lo, key_hi, key_lo, WqTh, WqTl, WkTh, WkTl,
            bq, bk, wcomb, q_hi, q_lo, qw_bf, k_hi, k_lo, 0);
    } else {
        // sequential fallback: q first (reads query_*), then k (overwrites query_* region)
        gemm_proj_f<<<dim3(8, 64, 1), 256, 0, stream>>>(
            query_hi, query_lo, key_hi, key_lo, WqTh, WqTl, WkTh, WkTl,
            bq, bk, wcomb, q_hi, q_lo, qw_bf, k_hi, k_lo, 0);
        gemm_proj_f<<<dim3(8, 64, 1), 256, 0, stream>>>(
            query_hi, query_lo, key_hi, key_lo, WqTh, WqTl, WkTh, WkTl,
            bq, bk, wcomb, q_hi, q_lo, qw_bf, k_hi, k_lo, 1);
    }

    transposeK<<<1024, 256, 0, stream>>>(k_hi, kT);

    // fat kernel: blocks 0..255 = combined-scores GEMM, 256..1279 = attention
    attn_comb<<<1280, 256, 0, stream>>>(q_hi, q_lo, k_hi, k_lo, kT, mbits, ctx,
                                        qw_bf, k_hi, bcomb, probs);

    softmax_rows<<<1024, 256, 0, stream>>>(probs);
    (void)in_sizes; (void)n_in; (void)out_size;
}

// Round 13
// 231.013 us; speedup vs baseline: 1.9859x; 1.0304x over previous
//
#include <hip/hip_runtime.h>
#include <hip/hip_bf16.h>

#define BB 4
#define SS 1024
#define DD 1024
#define HH 16

typedef __attribute__((ext_vector_type(8))) short bf16x8;
typedef __attribute__((ext_vector_type(4))) float f32x4;
typedef unsigned int u32;
typedef unsigned long long u64;

__device__ __forceinline__ ushort f2bf(float f) {
    u32 u = __builtin_bit_cast(u32, f);
    u32 r = (u + 0x7fffu + ((u >> 16) & 1u)) >> 16;
    return (ushort)r;
}
__device__ __forceinline__ float bf2f(ushort h) {
    return __builtin_bit_cast(float, (u32)h << 16);
}

__device__ __forceinline__ void gload16(const ushort* g, ushort* l) {
    __builtin_amdgcn_global_load_lds(
        (const __attribute__((address_space(1))) u32*)(const void*)g,
        (__attribute__((address_space(3))) u32*)(void*)l, 16, 0, 0);
}

// ---------------- convert f32 -> bf16 hi + lo residual (q and k fused) ----------------
__global__ __launch_bounds__(256) void cvt_split2(
    const float* __restrict__ q, const float* __restrict__ k,
    ushort* __restrict__ qh, ushort* __restrict__ ql,
    ushort* __restrict__ kh, ushort* __restrict__ kl) {
    int bid = blockIdx.x;
    const float* in;
    ushort *hi, *lo;
    if (bid < 4096) { in = q; hi = qh; lo = ql; }
    else            { in = k; hi = kh; lo = kl; bid -= 4096; }
    int i = (bid * 256 + threadIdx.x) * 4;
    float4 v = *(const float4*)(in + i);
    ushort4 h, l;
    float* pv = (float*)&v;
    ushort* ph = (ushort*)&h;
    ushort* pl = (ushort*)&l;
#pragma unroll
    for (int j = 0; j < 4; ++j) {
        ushort hh = f2bf(pv[j]);
        ph[j] = hh;
        pl[j] = f2bf(pv[j] - bf2f(hh));
    }
    *(ushort4*)(hi + i) = h;
    *(ushort4*)(lo + i) = l;
}

// ---------------- transpose W (f32 DxD) -> bf16 W^T hi/lo ----------------
__global__ __launch_bounds__(256) void transposeW_split(
    const float* __restrict__ Wq, const float* __restrict__ Wk,
    ushort* __restrict__ WqTh, ushort* __restrict__ WqTl,
    ushort* __restrict__ WkTh, ushort* __restrict__ WkTl) {
    __shared__ float tile[64][65];
    const float* W = blockIdx.z ? Wk : Wq;
    ushort* WTh = blockIdx.z ? WkTh : WqTh;
    ushort* WTl = blockIdx.z ? WkTl : WqTl;
    int kb = blockIdx.y * 64, nb = blockIdx.x * 64;
    int tid = threadIdx.x;
    int tx = tid & 63, ty = tid >> 6;
#pragma unroll
    for (int i = 0; i < 16; ++i) {
        int kl = ty * 16 + i;
        tile[kl][tx] = W[(size_t)(kb + kl) * DD + nb + tx];
    }
    __syncthreads();
#pragma unroll
    for (int i = 0; i < 16; ++i) {
        int nl = ty * 16 + i;
        float v = tile[tx][nl];
        ushort hh = f2bf(v);
        size_t idx = (size_t)(nb + nl) * DD + kb + tx;
        WTh[idx] = hh;
        WTl[idx] = f2bf(v - bf2f(hh));
    }
}

// ---------------- pack mask to bits ----------------
__global__ __launch_bounds__(256) void pack_mask(const int* __restrict__ mask,
                                                 u64* __restrict__ bits, int nwords) {
    int gw = (int)((blockIdx.x * 256 + threadIdx.x) >> 6);
    int lane = threadIdx.x & 63;
    if (gw < nwords) {
        int v = mask[(size_t)gw * 64 + lane];
        u64 m = __ballot(v != 0);
        if (lane == 0) bits[gw] = m;
    }
}

// ---------------- transpose k_hi per head-tile into tiled kT ----------------
__global__ __launch_bounds__(256) void transposeK(const ushort* __restrict__ kh,
                                                  ushort* __restrict__ kT) {
    __shared__ ushort t[64 * 66];
    int blk = blockIdx.x;
    const ushort* src = kh + (size_t)blk * 4096;
    ushort* dst = kT + (size_t)blk * 4096;
    int tid = threadIdx.x;
#pragma unroll
    for (int i = 0; i < 2; ++i) {
        int c = tid + 256 * i;
        int r = c >> 3, col = (c & 7) << 3;
        uint4 v = *(const uint4*)(src + (size_t)c * 8);
        const uint* pv = (const uint*)&v;
        *(uint*)(t + r * 66 + col + 0) = pv[0];
        *(uint*)(t + r * 66 + col + 2) = pv[1];
        *(uint*)(t + r * 66 + col + 4) = pv[2];
        *(uint*)(t + r * 66 + col + 6) = pv[3];
    }
    __syncthreads();
#pragma unroll
    for (int i = 0; i < 2; ++i) {
        int c = tid + 256 * i;
        int d = c >> 3, k0 = (c & 7) << 3;
        uint4 o;
        ushort* po = (ushort*)&o;
#pragma unroll
        for (int j = 0; j < 8; ++j) po[j] = t[(k0 + j) * 66 + d];
        *(uint4*)(dst + d * 64 + k0) = o;
    }
}

// ---------------- split-precision projection GEMM, q & k fused via blockIdx.z ----------
__global__ __launch_bounds__(256) void gemm_proj_f(
    const ushort* __restrict__ Aq_h, const ushort* __restrict__ Aq_l,
    const ushort* __restrict__ Ak_h, const ushort* __restrict__ Ak_l,
    const ushort* __restrict__ Bq_h, const ushort* __restrict__ Bq_l,
    const ushort* __restrict__ Bk_h, const ushort* __restrict__ Bk_l,
    const float* __restrict__ bq, const float* __restrict__ bk,
    const float* __restrict__ wcomb,
    ushort* __restrict__ Cq_hi, ushort* __restrict__ Cq_lo, ushort* __restrict__ Cw,
    ushort* __restrict__ Ck_hi, ushort* __restrict__ Ck_lo, int mode_base) {
    __shared__ __align__(16) ushort Ash[64 * 64];
    __shared__ __align__(16) ushort Asl[64 * 64];
    __shared__ __align__(16) ushort Bsh[128 * 64];
    __shared__ __align__(16) ushort Bsl[128 * 64];
    const int mode = blockIdx.z + mode_base;
    const ushort* Ah = mode ? Ak_h : Aq_h;
    const ushort* Al = mode ? Ak_l : Aq_l;
    const ushort* Bh = mode ? Bk_h : Bq_h;
    const ushort* Bl = mode ? Bk_l : Bq_l;
    const float* bias = mode ? bk : bq;
    ushort* Chi = mode ? Ck_hi : Cq_hi;
    ushort* Clo = mode ? Ck_lo : Cq_lo;
    const int tn = blockIdx.x, tm = blockIdx.y;
    const int tid = threadIdx.x, lane = tid & 63, w = tid >> 6;
    const int lr = lane >> 4, lc = lane & 15;
    f32x4 acc[8];
#pragma unroll
    for (int n = 0; n < 8; ++n) acc[n] = (f32x4){0.f, 0.f, 0.f, 0.f};

    for (int kt = 0; kt < DD; kt += 64) {
        __syncthreads();
#pragma unroll
        for (int i = 0; i < 2; ++i) {
            int c = tid + 256 * i;
            int r = c >> 3, col = (c & 7) << 3;
            size_t g = (size_t)(tm * 64 + r) * DD + kt + col;
            gload16(Ah + g, Ash + (w * 64 + 256 * i) * 8);
            gload16(Al + g, Asl + (w * 64 + 256 * i) * 8);
        }
#pragma unroll
        for (int i = 0; i < 4; ++i) {
            int c = tid + 256 * i;
            int r = c >> 3, col = (c & 7) << 3;
            size_t g = (size_t)(tn * 128 + r) * DD + kt + col;
            gload16(Bh + g, Bsh + (w * 64 + 256 * i) * 8);
            gload16(Bl + g, Bsl + (w * 64 + 256 * i) * 8);
        }
        __syncthreads();
#pragma unroll
        for (int t = 0; t < 2; ++t) {
            int aoff = (w * 16 + lc) * 64 + t * 32 + lr * 8;
            bf16x8 afh = *(const bf16x8*)(Ash + aoff);
            bf16x8 afl = *(const bf16x8*)(Asl + aoff);
#pragma unroll
            for (int n = 0; n < 8; ++n) {
                int boff = (n * 16 + lc) * 64 + t * 32 + lr * 8;
                bf16x8 bfh = *(const bf16x8*)(Bsh + boff);
                bf16x8 bfl = *(const bf16x8*)(Bsl + boff);
                acc[n] = __builtin_amdgcn_mfma_f32_16x16x32_bf16(afh, bfh, acc[n], 0, 0, 0);
                acc[n] = __builtin_amdgcn_mfma_f32_16x16x32_bf16(afh, bfl, acc[n], 0, 0, 0);
                acc[n] = __builtin_amdgcn_mfma_f32_16x16x32_bf16(afl, bfh, acc[n], 0, 0, 0);
            }
        }
    }
#pragma unroll
    for (int n = 0; n < 8; ++n) {
        int gcol = tn * 128 + n * 16 + lc;
#pragma unroll
        for (int r = 0; r < 4; ++r) {
            int grow = tm * 64 + w * 16 + lr * 4 + r;
            float v = acc[n][r] + bias[gcol];
            size_t idx = (size_t)grow * DD + gcol;
            ushort hh = f2bf(v);
            Chi[idx] = hh;
            Clo[idx] = f2bf(v - bf2f(hh));
            if (mode == 0) Cw[idx] = f2bf(v * wcomb[(grow >> 6) & 15]);
        }
    }
}

// swizzled LDS frag address (ushort units): row rr, 16B-block bi
#define SWZ(rr, bi) (((rr) << 6) + ((((bi) ^ ((rr) & 7))) << 3))

// ---------------- FAT kernel: gemm_comb (blocks 0..255) || attn (blocks 256..1279) ----
__global__ __launch_bounds__(256) void attn_comb(
    const ushort* __restrict__ qh_, const ushort* __restrict__ ql_,
    const ushort* __restrict__ kh_, const ushort* __restrict__ kl_,
    const ushort* __restrict__ kT_, const u64* __restrict__ mbits,
    float* __restrict__ ctx,
    const ushort* __restrict__ Aq, const ushort* __restrict__ Bk,
    const float* __restrict__ bcomb, float* __restrict__ probs) {
    __shared__ __align__(16) ushort shm[28928];  // 57,856 B
    const int bid = blockIdx.x;
    const int tid = threadIdx.x, lane = tid & 63, w = tid >> 6;
    const int lr = lane >> 4, lc = lane & 15;

    if (bid < 256) {
        // ---------------- combined-scores GEMM (swizzled staging; r11/r12-validated) --
        ushort* As = shm;           // 128x64 swizzled
        ushort* Bs = shm + 8192;
        const int tn = bid & 7, tm = (bid >> 3) & 7, bz = bid >> 6;
        const ushort* Ab = Aq + (size_t)bz * SS * DD;
        const ushort* Bb = Bk + (size_t)bz * SS * DD;
        const int wm = w >> 1, wn = w & 1;
        f32x4 acc[4][4];
#pragma unroll
        for (int m = 0; m < 4; ++m)
#pragma unroll
            for (int n = 0; n < 4; ++n) acc[m][n] = (f32x4){0.f, 0.f, 0.f, 0.f};

        for (int h = 0; h < HH; ++h) {
            __syncthreads();
            const ushort* Asrc = Ab + (size_t)h * 65536 + tm * 8192;
            const ushort* Bsrc = Bb + (size_t)h * 65536 + tn * 8192;
#pragma unroll
            for (int i = 0; i < 4; ++i) {
                int ch = (w << 2) + i;                      // chunk 0..15 (1024B)
                int row = (ch << 3) + (lane >> 3);          // 0..127
                int blkk = (lane & 7) ^ ((lane >> 3) & 7);  // swizzled 16B block
                size_t g = (size_t)row * 64 + blkk * 8;
                gload16(Asrc + g, As + ch * 512);
                gload16(Bsrc + g, Bs + ch * 512);
            }
            __syncthreads();
#pragma unroll
            for (int t = 0; t < 2; ++t) {
                bf16x8 af[4], bfr[4];
#pragma unroll
                for (int m = 0; m < 4; ++m)
                    af[m] = *(const bf16x8*)(As + SWZ(wm * 64 + m * 16 + lc, t * 4 + lr));
#pragma unroll
                for (int n = 0; n < 4; ++n)
                    bfr[n] = *(const bf16x8*)(Bs + SWZ(wn * 64 + n * 16 + lc, t * 4 + lr));
#pragma unroll
                for (int m = 0; m < 4; ++m)
#pragma unroll
                    for (int n = 0; n < 4; ++n)
                        acc[m][n] = __builtin_amdgcn_mfma_f32_16x16x32_bf16(af[m], bfr[n], acc[m][n], 0, 0, 0);
            }
        }
        float b0 = bcomb[0];
#pragma unroll
        for (int m = 0; m < 4; ++m) {
            int grow0 = tm * 128 + wm * 64 + m * 16 + lr * 4;
#pragma unroll
            for (int n = 0; n < 4; ++n) {
                int gcol = tn * 128 + wn * 64 + n * 16 + lc;
#pragma unroll
                for (int r = 0; r < 4; ++r)
                    probs[(size_t)bz * SS * SS + (size_t)(grow0 + r) * SS + gcol] = acc[m][n][r] + b0;
            }
        }
        return;
    }

    // ---------------- flash attention (V = K): r10-proven softmax, deferred row-sum ---
    const int abid = bid - 256;
    const int qt = abid & 15, h = (abid >> 4) & 15, b = abid >> 8;
    ushort* KbBase = shm;          // [2][3][4096]
    ushort* PsBase = shm + 24576;  // [4][16*68]
    const int bh = b * HH + h;
    const size_t headbase = (size_t)bh * (SS * 64);

    auto KB = [&](int buf, int j) -> ushort* { return KbBase + (buf * 3 + j) * 4096; };
    auto stage = [&](int buf, int kt) {
#pragma unroll
        for (int i = 0; i < 2; ++i) {
            int ch = (w << 1) + i;
            int row = (ch << 3) + (lane >> 3);
            int blkk = (lane & 7) ^ ((lane >> 3) & 7);
            size_t g = ((size_t)bh * 16 + kt) * 4096 + (size_t)row * 64 + blkk * 8;
            gload16(kh_ + g, KB(buf, 0) + ch * 512);
            gload16(kl_ + g, KB(buf, 1) + ch * 512);
            gload16(kT_ + g, KB(buf, 2) + ch * 512);
        }
    };

    bf16x8 qfh[2], qfl[2];
    {
        size_t rowoff = headbase + (size_t)(qt * 64 + w * 16 + lc) * 64;
#pragma unroll
        for (int t = 0; t < 2; ++t) {
            qfh[t] = *(const bf16x8*)(qh_ + rowoff + t * 32 + lr * 8);
            qfl[t] = *(const bf16x8*)(ql_ + rowoff + t * 32 + lr * 8);
        }
    }
    f32x4 acc[4];
#pragma unroll
    for (int dt = 0; dt < 4; ++dt) acc[dt] = (f32x4){0.f, 0.f, 0.f, 0.f};
    float mrow[4] = {-3e38f, -3e38f, -3e38f, -3e38f};
    float lsum[4] = {0.f, 0.f, 0.f, 0.f};  // per-lane partial (scale is row-uniform)

    stage(0, 0);
    __syncthreads();
    int cur = 0;

    for (int kt = 0; kt < 16; ++kt) {
        if (kt < 15) stage(cur ^ 1, kt + 1);  // prefetch next (hidden under compute)

        const ushort* Bh = KB(cur, 0);
        const ushort* Bl = KB(cur, 1);
        const ushort* Vt = KB(cur, 2);

        // QK^T (split precision): s = qh*kh + qh*kl + ql*kh
        f32x4 sc[4];
#pragma unroll
        for (int nt = 0; nt < 4; ++nt) {
            f32x4 z = (f32x4){0.f, 0.f, 0.f, 0.f};
            __builtin_amdgcn_s_setprio(1);
#pragma unroll
            for (int t = 0; t < 2; ++t) {
                bf16x8 kfh = *(const bf16x8*)(Bh + SWZ(nt * 16 + lc, t * 4 + lr));
                bf16x8 kfl = *(const bf16x8*)(Bl + SWZ(nt * 16 + lc, t * 4 + lr));
                z = __builtin_amdgcn_mfma_f32_16x16x32_bf16(qfh[t], kfh, z, 0, 0, 0);
                z = __builtin_amdgcn_mfma_f32_16x16x32_bf16(qfh[t], kfl, z, 0, 0, 0);
                z = __builtin_amdgcn_mfma_f32_16x16x32_bf16(qfl[t], kfh, z, 0, 0, 0);
            }
            __builtin_amdgcn_s_setprio(0);
            sc[nt] = z;
        }

        // mask + online softmax: rmax shfl (proven), rsum DEFERRED to per-lane partial
#pragma unroll
        for (int r = 0; r < 4; ++r) {
            u64 wbit = mbits[((size_t)b * SS + qt * 64 + w * 16 + lr * 4 + r) * 16 + kt];
            float rmax = -3e38f;
#pragma unroll
            for (int nt = 0; nt < 4; ++nt) {
                int kkloc = nt * 16 + lc;
                float v = sc[nt][r];
                v = ((wbit >> kkloc) & 1ULL) ? v : -3e38f;
                sc[nt][r] = v;
                rmax = fmaxf(rmax, v);
            }
#pragma unroll
            for (int d2 = 1; d2 < 16; d2 <<= 1) rmax = fmaxf(rmax, __shfl_xor(rmax, d2, 64));
            float mnew = fmaxf(mrow[r], rmax);
            float scale = __expf(mrow[r] - mnew);
            float rsum = 0.f;
#pragma unroll
            for (int nt = 0; nt < 4; ++nt) {
                float p = __expf(sc[nt][r] - mnew);
                sc[nt][r] = p;
                rsum += p;
            }
            lsum[r] = lsum[r] * scale + rsum;  // per-lane; summed across lanes at end
            mrow[r] = mnew;
#pragma unroll
            for (int dt = 0; dt < 4; ++dt) acc[dt][r] *= scale;
        }

        // P -> per-wave LDS (C/D layout -> A-frag layout), pitch 68, RNE pack (proven)
        ushort* P = PsBase + w * 1088;
#pragma unroll
        for (int nt = 0; nt < 4; ++nt)
#pragma unroll
            for (int r = 0; r < 4; ++r)
                P[(lr * 4 + r) * 68 + nt * 16 + lc] = f2bf(sc[nt][r]);
        asm volatile("s_waitcnt lgkmcnt(0)" ::: "memory");
        __builtin_amdgcn_sched_barrier(0);

        bf16x8 pf[2];
#pragma unroll
        for (int t = 0; t < 2; ++t)
            pf[t] = *(const bf16x8*)(P + lc * 68 + t * 32 + lr * 8);

        // PV: context += P @ K_tile (V = K hi, from pre-transposed kT)
        __builtin_amdgcn_s_setprio(1);
#pragma unroll
        for (int dt = 0; dt < 4; ++dt) {
#pragma unroll
            for (int t = 0; t < 2; ++t) {
                bf16x8 vf = *(const bf16x8*)(Vt + SWZ(dt * 16 + lc, t * 4 + lr));
                acc[dt] = __builtin_amdgcn_mfma_f32_16x16x32_bf16(pf[t], vf, acc[dt], 0, 0, 0);
            }
        }
        __builtin_amdgcn_s_setprio(0);

        if (kt < 15) __syncthreads();  // drains vmcnt (stage) + syncs buffers
        cur ^= 1;
    }

    // epilogue: one lsum reduction across the 16-lane row group (proven shfl butterfly)
#pragma unroll
    for (int r = 0; r < 4; ++r) {
#pragma unroll
        for (int d2 = 1; d2 < 16; d2 <<= 1) lsum[r] += __shfl_xor(lsum[r], d2, 64);
        float inv = (lsum[r] > 0.f) ? 1.f / lsum[r] : 0.f;
        int q = qt * 64 + w * 16 + lr * 4 + r;
#pragma unroll
        for (int dt = 0; dt < 4; ++dt)
            ctx[(((size_t)bh) * SS + q) * 64 + dt * 16 + lc] = acc[dt][r] * inv;
    }
}

// ---------------- row softmax for probs ----------------
__global__ __launch_bounds__(256) void softmax_rows(float* __restrict__ data) {
    int w = threadIdx.x >> 6, lane = threadIdx.x & 63;
    float* p = data + ((size_t)blockIdx.x * 4 + w) * SS;
    float4 v[4];
    float mx = -3e38f;
#pragma unroll
    for (int i = 0; i < 4; ++i) {
        v[i] = *(const float4*)(p + i * 256 + lane * 4);
        mx = fmaxf(mx, fmaxf(fmaxf(v[i].x, v[i].y), fmaxf(v[i].z, v[i].w)));
    }
#pragma unroll
    for (int d2 = 1; d2 < 64; d2 <<= 1) mx = fmaxf(mx, __shfl_xor(mx, d2, 64));
    float sum = 0.f;
#pragma unroll
    for (int i = 0; i < 4; ++i) {
        v[i].x = __expf(v[i].x - mx);
        v[i].y = __expf(v[i].y - mx);
        v[i].z = __expf(v[i].z - mx);
        v[i].w = __expf(v[i].w - mx);
        sum += v[i].x + v[i].y + v[i].z + v[i].w;
    }
#pragma unroll
    for (int d2 = 1; d2 < 64; d2 <<= 1) sum += __shfl_xor(sum, d2, 64);
    float inv = 1.f / sum;
#pragma unroll
    for (int i = 0; i < 4; ++i) {
        v[i].x *= inv; v[i].y *= inv; v[i].z *= inv; v[i].w *= inv;
        *(float4*)(p + i * 256 + lane * 4) = v[i];
    }
}

extern "C" void kernel_launch(void* const* d_in, const int* in_sizes, int n_in,
                              void* d_out, int out_size, void* d_ws, size_t ws_size,
                              hipStream_t stream) {
    const float* query = (const float*)d_in[0];
    const float* key   = (const float*)d_in[1];
    const int*   mask  = (const int*)d_in[2];
    const float* Wq    = (const float*)d_in[3];
    const float* bq    = (const float*)d_in[4];
    const float* Wk    = (const float*)d_in[5];
    const float* bk    = (const float*)d_in[6];
    const float* wcomb = (const float*)d_in[7];
    const float* bcomb = (const float*)d_in[8];
    float* probs = (float*)d_out;                          // (B,S,S)
    float* ctx   = (float*)d_out + (size_t)BB * SS * SS;   // (B,H,S,DK) flat

    char* ws = (char*)d_ws;
    const size_t MB = 1ull << 20;
    ushort* query_hi = (ushort*)(ws);             // [0,8)
    ushort* query_lo = (ushort*)(ws + 8 * MB);    // [8,16)
    ushort* key_hi   = (ushort*)(ws + 16 * MB);   // [16,24)
    ushort* key_lo   = (ushort*)(ws + 24 * MB);   // [24,32)
    ushort* WqTh     = (ushort*)(ws + 32 * MB);   // [32,34)
    ushort* WqTl     = (ushort*)(ws + 34 * MB);   // [34,36)
    ushort* WkTh     = (ushort*)(ws + 36 * MB);   // [36,38)
    ushort* WkTl     = (ushort*)(ws + 38 * MB);   // [38,40)
    ushort* qw_bf    = (ushort*)(ws + 40 * MB);   // [40,48)
    ushort* q_hi     = (ushort*)(ws + 48 * MB);   // [48,56)
    ushort* q_lo     = (ushort*)(ws + 56 * MB);   // [56,64)
    u64*    mbits    = (u64*)(ws + 64 * MB);      // [64,64.5)
    ushort* kT       = (ushort*)(ws + 65 * MB);   // [65,73)

    const bool bigws = ws_size >= 90 * MB;
    ushort* k_hi = bigws ? (ushort*)(ws + 73 * MB) : (ushort*)(ws);
    ushort* k_lo = bigws ? (ushort*)(ws + 81 * MB) : (ushort*)(ws + 8 * MB);

    cvt_split2<<<8192, 256, 0, stream>>>(query, key, query_hi, query_lo, key_hi, key_lo);
    transposeW_split<<<dim3(16, 16, 2), 256, 0, stream>>>(Wq, Wk, WqTh, WqTl, WkTh, WkTl);
    pack_mask<<<16384, 256, 0, stream>>>(mask, mbits, BB * SS * (SS / 64));

    if (bigws) {
        gemm_proj_f<<<dim3(8, 64, 2), 256, 0, stream>>>(
            query_hi, query_lo, key_hi, key_lo, WqTh, WqTl, WkTh, WkTl,
            bq, bk, wcomb, q_hi, q_lo, qw_bf, k_hi, k_lo, 0);
    } else {
        gemm_proj_f<<<dim3(8, 64, 1), 256, 0, stream>>>(
            query_hi, query_lo, key_hi, key_lo, WqTh, WqTl, WkTh, WkTl,
            bq, bk, wcomb, q_hi, q_lo, qw_bf, k_hi, k_lo, 0);
        gemm_proj_f<<<dim3(8, 64, 1), 256, 0, stream>>>(
            query_hi, query_lo, key_hi, key_lo, WqTh, WqTl, WkTh, WkTl,
            bq, bk, wcomb, q_hi, q_lo, qw_bf, k_hi, k_lo, 1);
    }

    transposeK<<<1024, 256, 0, stream>>>(k_hi, kT);

    attn_comb<<<1280, 256, 0, stream>>>(q_hi, q_lo, k_hi, k_lo, kT, mbits, ctx,
                                        qw_bf, k_hi, bcomb, probs);

    softmax_rows<<<1024, 256, 0, stream>>>(probs);
    (void)in_sizes; (void)n_in; (void)out_size;
}

// Round 14
// 222.471 us; speedup vs baseline: 2.0622x; 1.0384x over previous
//
#include <hip/hip_runtime.h>
#include <hip/hip_bf16.h>

#define BB 4
#define SS 1024
#define DD 1024
#define HH 16

typedef __attribute__((ext_vector_type(8))) short bf16x8;
typedef __attribute__((ext_vector_type(4))) float f32x4;
typedef unsigned int u32;
typedef unsigned long long u64;

__device__ __forceinline__ ushort f2bf(float f) {
    u32 u = __builtin_bit_cast(u32, f);
    u32 r = (u + 0x7fffu + ((u >> 16) & 1u)) >> 16;
    return (ushort)r;
}
__device__ __forceinline__ float bf2f(ushort h) {
    return __builtin_bit_cast(float, (u32)h << 16);
}

__device__ __forceinline__ void gload16(const ushort* g, ushort* l) {
    __builtin_amdgcn_global_load_lds(
        (const __attribute__((address_space(1))) u32*)(const void*)g,
        (__attribute__((address_space(3))) u32*)(void*)l, 16, 0, 0);
}

// ---------------- convert f32 -> bf16 hi + lo residual (q and k fused) ----------------
__global__ __launch_bounds__(256) void cvt_split2(
    const float* __restrict__ q, const float* __restrict__ k,
    ushort* __restrict__ qh, ushort* __restrict__ ql,
    ushort* __restrict__ kh, ushort* __restrict__ kl) {
    int bid = blockIdx.x;
    const float* in;
    ushort *hi, *lo;
    if (bid < 4096) { in = q; hi = qh; lo = ql; }
    else            { in = k; hi = kh; lo = kl; bid -= 4096; }
    int i = (bid * 256 + threadIdx.x) * 4;
    float4 v = *(const float4*)(in + i);
    ushort4 h, l;
    float* pv = (float*)&v;
    ushort* ph = (ushort*)&h;
    ushort* pl = (ushort*)&l;
#pragma unroll
    for (int j = 0; j < 4; ++j) {
        ushort hh = f2bf(pv[j]);
        ph[j] = hh;
        pl[j] = f2bf(pv[j] - bf2f(hh));
    }
    *(ushort4*)(hi + i) = h;
    *(ushort4*)(lo + i) = l;
}

// ---------------- transpose W (f32 DxD) -> bf16 W^T hi/lo ----------------
__global__ __launch_bounds__(256) void transposeW_split(
    const float* __restrict__ Wq, const float* __restrict__ Wk,
    ushort* __restrict__ WqTh, ushort* __restrict__ WqTl,
    ushort* __restrict__ WkTh, ushort* __restrict__ WkTl) {
    __shared__ float tile[64][65];
    const float* W = blockIdx.z ? Wk : Wq;
    ushort* WTh = blockIdx.z ? WkTh : WqTh;
    ushort* WTl = blockIdx.z ? WkTl : WqTl;
    int kb = blockIdx.y * 64, nb = blockIdx.x * 64;
    int tid = threadIdx.x;
    int tx = tid & 63, ty = tid >> 6;
#pragma unroll
    for (int i = 0; i < 16; ++i) {
        int kl = ty * 16 + i;
        tile[kl][tx] = W[(size_t)(kb + kl) * DD + nb + tx];
    }
    __syncthreads();
#pragma unroll
    for (int i = 0; i < 16; ++i) {
        int nl = ty * 16 + i;
        float v = tile[tx][nl];
        ushort hh = f2bf(v);
        size_t idx = (size_t)(nb + nl) * DD + kb + tx;
        WTh[idx] = hh;
        WTl[idx] = f2bf(v - bf2f(hh));
    }
}

// ---------------- pack mask to bits ----------------
__global__ __launch_bounds__(256) void pack_mask(const int* __restrict__ mask,
                                                 u64* __restrict__ bits, int nwords) {
    int gw = (int)((blockIdx.x * 256 + threadIdx.x) >> 6);
    int lane = threadIdx.x & 63;
    if (gw < nwords) {
        int v = mask[(size_t)gw * 64 + lane];
        u64 m = __ballot(v != 0);
        if (lane == 0) bits[gw] = m;
    }
}

// ---------------- transpose k_hi per head-tile into tiled kT ----------------
__global__ __launch_bounds__(256) void transposeK(const ushort* __restrict__ kh,
                                                  ushort* __restrict__ kT) {
    __shared__ ushort t[64 * 66];
    int blk = blockIdx.x;
    const ushort* src = kh + (size_t)blk * 4096;
    ushort* dst = kT + (size_t)blk * 4096;
    int tid = threadIdx.x;
#pragma unroll
    for (int i = 0; i < 2; ++i) {
        int c = tid + 256 * i;
        int r = c >> 3, col = (c & 7) << 3;
        uint4 v = *(const uint4*)(src + (size_t)c * 8);
        const uint* pv = (const uint*)&v;
        *(uint*)(t + r * 66 + col + 0) = pv[0];
        *(uint*)(t + r * 66 + col + 2) = pv[1];
        *(uint*)(t + r * 66 + col + 4) = pv[2];
        *(uint*)(t + r * 66 + col + 6) = pv[3];
    }
    __syncthreads();
#pragma unroll
    for (int i = 0; i < 2; ++i) {
        int c = tid + 256 * i;
        int d = c >> 3, k0 = (c & 7) << 3;
        uint4 o;
        ushort* po = (ushort*)&o;
#pragma unroll
        for (int j = 0; j < 8; ++j) po[j] = t[(k0 + j) * 66 + d];
        *(uint4*)(dst + d * 64 + k0) = o;
    }
}

// ---------------- split-precision projection GEMM, q & k fused via blockIdx.z ----------
__global__ __launch_bounds__(256) void gemm_proj_f(
    const ushort* __restrict__ Aq_h, const ushort* __restrict__ Aq_l,
    const ushort* __restrict__ Ak_h, const ushort* __restrict__ Ak_l,
    const ushort* __restrict__ Bq_h, const ushort* __restrict__ Bq_l,
    const ushort* __restrict__ Bk_h, const ushort* __restrict__ Bk_l,
    const float* __restrict__ bq, const float* __restrict__ bk,
    const float* __restrict__ wcomb,
    ushort* __restrict__ Cq_hi, ushort* __restrict__ Cq_lo, ushort* __restrict__ Cw,
    ushort* __restrict__ Ck_hi, ushort* __restrict__ Ck_lo, int mode_base) {
    __shared__ __align__(16) ushort Ash[64 * 64];
    __shared__ __align__(16) ushort Asl[64 * 64];
    __shared__ __align__(16) ushort Bsh[128 * 64];
    __shared__ __align__(16) ushort Bsl[128 * 64];
    const int mode = blockIdx.z + mode_base;
    const ushort* Ah = mode ? Ak_h : Aq_h;
    const ushort* Al = mode ? Ak_l : Aq_l;
    const ushort* Bh = mode ? Bk_h : Bq_h;
    const ushort* Bl = mode ? Bk_l : Bq_l;
    const float* bias = mode ? bk : bq;
    ushort* Chi = mode ? Ck_hi : Cq_hi;
    ushort* Clo = mode ? Ck_lo : Cq_lo;
    const int tn = blockIdx.x, tm = blockIdx.y;
    const int tid = threadIdx.x, lane = tid & 63, w = tid >> 6;
    const int lr = lane >> 4, lc = lane & 15;
    f32x4 acc[8];
#pragma unroll
    for (int n = 0; n < 8; ++n) acc[n] = (f32x4){0.f, 0.f, 0.f, 0.f};

    for (int kt = 0; kt < DD; kt += 64) {
        __syncthreads();
#pragma unroll
        for (int i = 0; i < 2; ++i) {
            int c = tid + 256 * i;
            int r = c >> 3, col = (c & 7) << 3;
            size_t g = (size_t)(tm * 64 + r) * DD + kt + col;
            gload16(Ah + g, Ash + (w * 64 + 256 * i) * 8);
            gload16(Al + g, Asl + (w * 64 + 256 * i) * 8);
        }
#pragma unroll
        for (int i = 0; i < 4; ++i) {
            int c = tid + 256 * i;
            int r = c >> 3, col = (c & 7) << 3;
            size_t g = (size_t)(tn * 128 + r) * DD + kt + col;
            gload16(Bh + g, Bsh + (w * 64 + 256 * i) * 8);
            gload16(Bl + g, Bsl + (w * 64 + 256 * i) * 8);
        }
        __syncthreads();
#pragma unroll
        for (int t = 0; t < 2; ++t) {
            int aoff = (w * 16 + lc) * 64 + t * 32 + lr * 8;
            bf16x8 afh = *(const bf16x8*)(Ash + aoff);
            bf16x8 afl = *(const bf16x8*)(Asl + aoff);
#pragma unroll
            for (int n = 0; n < 8; ++n) {
                int boff = (n * 16 + lc) * 64 + t * 32 + lr * 8;
                bf16x8 bfh = *(const bf16x8*)(Bsh + boff);
                bf16x8 bfl = *(const bf16x8*)(Bsl + boff);
                acc[n] = __builtin_amdgcn_mfma_f32_16x16x32_bf16(afh, bfh, acc[n], 0, 0, 0);
                acc[n] = __builtin_amdgcn_mfma_f32_16x16x32_bf16(afh, bfl, acc[n], 0, 0, 0);
                acc[n] = __builtin_amdgcn_mfma_f32_16x16x32_bf16(afl, bfh, acc[n], 0, 0, 0);
            }
        }
    }
#pragma unroll
    for (int n = 0; n < 8; ++n) {
        int gcol = tn * 128 + n * 16 + lc;
#pragma unroll
        for (int r = 0; r < 4; ++r) {
            int grow = tm * 64 + w * 16 + lr * 4 + r;
            float v = acc[n][r] + bias[gcol];
            size_t idx = (size_t)grow * DD + gcol;
            ushort hh = f2bf(v);
            Chi[idx] = hh;
            Clo[idx] = f2bf(v - bf2f(hh));
            if (mode == 0) Cw[idx] = f2bf(v * wcomb[(grow >> 6) & 15]);
        }
    }
}

// swizzled LDS frag address (ushort units): row rr, 16B-block bi
#define SWZ(rr, bi) (((rr) << 6) + ((((bi) ^ ((rr) & 7))) << 3))

// ---------------- FAT kernel: gemm_comb (blocks 0..255) || attn (blocks 256..1279) ----
// attn LDS = 48 KB exactly (3 blocks/CU): P aliases the dead kh tile after QK^T,
// guarded by a RAW s_barrier (no vmcnt drain -> prefetch stays in flight).
__global__ __launch_bounds__(256) void attn_comb(
    const ushort* __restrict__ qh_, const ushort* __restrict__ ql_,
    const ushort* __restrict__ kh_, const ushort* __restrict__ kl_,
    const ushort* __restrict__ kT_, const u64* __restrict__ mbits,
    float* __restrict__ ctx,
    const ushort* __restrict__ Aq, const ushort* __restrict__ Bk,
    const float* __restrict__ bcomb, float* __restrict__ probs) {
    __shared__ __align__(16) ushort shm[24576];  // 49,152 B
    const int bid = blockIdx.x;
    const int tid = threadIdx.x, lane = tid & 63, w = tid >> 6;
    const int lr = lane >> 4, lc = lane & 15;

    if (bid < 256) {
        // ---------------- combined-scores GEMM (swizzled staging; r13-proven) ---------
        ushort* As = shm;           // 128x64 swizzled
        ushort* Bs = shm + 8192;
        const int tn = bid & 7, tm = (bid >> 3) & 7, bz = bid >> 6;
        const ushort* Ab = Aq + (size_t)bz * SS * DD;
        const ushort* Bb = Bk + (size_t)bz * SS * DD;
        const int wm = w >> 1, wn = w & 1;
        f32x4 acc[4][4];
#pragma unroll
        for (int m = 0; m < 4; ++m)
#pragma unroll
            for (int n = 0; n < 4; ++n) acc[m][n] = (f32x4){0.f, 0.f, 0.f, 0.f};

        for (int h = 0; h < HH; ++h) {
            __syncthreads();
            const ushort* Asrc = Ab + (size_t)h * 65536 + tm * 8192;
            const ushort* Bsrc = Bb + (size_t)h * 65536 + tn * 8192;
#pragma unroll
            for (int i = 0; i < 4; ++i) {
                int ch = (w << 2) + i;                      // chunk 0..15 (1024B)
                int row = (ch << 3) + (lane >> 3);          // 0..127
                int blkk = (lane & 7) ^ ((lane >> 3) & 7);  // swizzled 16B block
                size_t g = (size_t)row * 64 + blkk * 8;
                gload16(Asrc + g, As + ch * 512);
                gload16(Bsrc + g, Bs + ch * 512);
            }
            __syncthreads();
#pragma unroll
            for (int t = 0; t < 2; ++t) {
                bf16x8 af[4], bfr[4];
#pragma unroll
                for (int m = 0; m < 4; ++m)
                    af[m] = *(const bf16x8*)(As + SWZ(wm * 64 + m * 16 + lc, t * 4 + lr));
#pragma unroll
                for (int n = 0; n < 4; ++n)
                    bfr[n] = *(const bf16x8*)(Bs + SWZ(wn * 64 + n * 16 + lc, t * 4 + lr));
#pragma unroll
                for (int m = 0; m < 4; ++m)
#pragma unroll
                    for (int n = 0; n < 4; ++n)
                        acc[m][n] = __builtin_amdgcn_mfma_f32_16x16x32_bf16(af[m], bfr[n], acc[m][n], 0, 0, 0);
            }
        }
        float b0 = bcomb[0];
#pragma unroll
        for (int m = 0; m < 4; ++m) {
            int grow0 = tm * 128 + wm * 64 + m * 16 + lr * 4;
#pragma unroll
            for (int n = 0; n < 4; ++n) {
                int gcol = tn * 128 + wn * 64 + n * 16 + lc;
#pragma unroll
                for (int r = 0; r < 4; ++r)
                    probs[(size_t)bz * SS * SS + (size_t)(grow0 + r) * SS + gcol] = acc[m][n][r] + b0;
            }
        }
        return;
    }

    // ---------------- flash attention (V = K): r13-proven math, P aliased into kh ----
    const int abid = bid - 256;
    const int qt = abid & 15, h = (abid >> 4) & 15, b = abid >> 8;
    ushort* KbBase = shm;          // [2][3][4096] = 48 KB
    const int bh = b * HH + h;
    const size_t headbase = (size_t)bh * (SS * 64);

    auto KB = [&](int buf, int j) -> ushort* { return KbBase + (buf * 3 + j) * 4096; };
    auto stage = [&](int buf, int kt) {
#pragma unroll
        for (int i = 0; i < 2; ++i) {
            int ch = (w << 1) + i;
            int row = (ch << 3) + (lane >> 3);
            int blkk = (lane & 7) ^ ((lane >> 3) & 7);
            size_t g = ((size_t)bh * 16 + kt) * 4096 + (size_t)row * 64 + blkk * 8;
            gload16(kh_ + g, KB(buf, 0) + ch * 512);
            gload16(kl_ + g, KB(buf, 1) + ch * 512);
            gload16(kT_ + g, KB(buf, 2) + ch * 512);
        }
    };

    bf16x8 qfh[2], qfl[2];
    {
        size_t rowoff = headbase + (size_t)(qt * 64 + w * 16 + lc) * 64;
#pragma unroll
        for (int t = 0; t < 2; ++t) {
            qfh[t] = *(const bf16x8*)(qh_ + rowoff + t * 32 + lr * 8);
            qfl[t] = *(const bf16x8*)(ql_ + rowoff + t * 32 + lr * 8);
        }
    }
    f32x4 acc[4];
#pragma unroll
    for (int dt = 0; dt < 4; ++dt) acc[dt] = (f32x4){0.f, 0.f, 0.f, 0.f};
    float mrow[4] = {-3e38f, -3e38f, -3e38f, -3e38f};
    float lsum[4] = {0.f, 0.f, 0.f, 0.f};  // per-lane partial (scale is row-uniform)

    stage(0, 0);
    __syncthreads();
    int cur = 0;

    for (int kt = 0; kt < 16; ++kt) {
        if (kt < 15) stage(cur ^ 1, kt + 1);  // prefetch next (hidden under compute)

        const ushort* Bh = KB(cur, 0);
        const ushort* Bl = KB(cur, 1);
        const ushort* Vt = KB(cur, 2);

        // QK^T (split precision): s = qh*kh + qh*kl + ql*kh
        f32x4 sc[4];
#pragma unroll
        for (int nt = 0; nt < 4; ++nt) {
            f32x4 z = (f32x4){0.f, 0.f, 0.f, 0.f};
            __builtin_amdgcn_s_setprio(1);
#pragma unroll
            for (int t = 0; t < 2; ++t) {
                bf16x8 kfh = *(const bf16x8*)(Bh + SWZ(nt * 16 + lc, t * 4 + lr));
                bf16x8 kfl = *(const bf16x8*)(Bl + SWZ(nt * 16 + lc, t * 4 + lr));
                z = __builtin_amdgcn_mfma_f32_16x16x32_bf16(qfh[t], kfh, z, 0, 0, 0);
                z = __builtin_amdgcn_mfma_f32_16x16x32_bf16(qfh[t], kfl, z, 0, 0, 0);
                z = __builtin_amdgcn_mfma_f32_16x16x32_bf16(qfl[t], kfh, z, 0, 0, 0);
            }
            __builtin_amdgcn_s_setprio(0);
            sc[nt] = z;
        }

        // mask + online softmax: rmax shfl (proven), rsum deferred to per-lane partial
#pragma unroll
        for (int r = 0; r < 4; ++r) {
            u64 wbit = mbits[((size_t)b * SS + qt * 64 + w * 16 + lr * 4 + r) * 16 + kt];
            float rmax = -3e38f;
#pragma unroll
            for (int nt = 0; nt < 4; ++nt) {
                int kkloc = nt * 16 + lc;
                float v = sc[nt][r];
                v = ((wbit >> kkloc) & 1ULL) ? v : -3e38f;
                sc[nt][r] = v;
                rmax = fmaxf(rmax, v);
            }
#pragma unroll
            for (int d2 = 1; d2 < 16; d2 <<= 1) rmax = fmaxf(rmax, __shfl_xor(rmax, d2, 64));
            float mnew = fmaxf(mrow[r], rmax);
            float scale = __expf(mrow[r] - mnew);
            float rsum = 0.f;
#pragma unroll
            for (int nt = 0; nt < 4; ++nt) {
                float p = __expf(sc[nt][r] - mnew);
                sc[nt][r] = p;
                rsum += p;
            }
            lsum[r] = lsum[r] * scale + rsum;  // per-lane; summed across lanes at end
            mrow[r] = mnew;
#pragma unroll
            for (int dt = 0; dt < 4; ++dt) acc[dt][r] *= scale;
        }

        // RAW barrier: all waves' kh reads done before P overwrites kh.
        // (No vmcnt drain -> the stage() prefetch stays in flight.)
        __builtin_amdgcn_s_barrier();
        __builtin_amdgcn_sched_barrier(0);

        // P -> aliased kh slice (wave-private 16x64, SWZ-swizzled), RNE pack (proven)
        ushort* P = KB(cur, 0) + w * 1024;
#pragma unroll
        for (int nt = 0; nt < 4; ++nt)
#pragma unroll
            for (int r = 0; r < 4; ++r) {
                int lrow = lr * 4 + r;
                P[SWZ(lrow, nt * 2 + (lc >> 3)) + (lc & 7)] = f2bf(sc[nt][r]);
            }
        asm volatile("s_waitcnt lgkmcnt(0)" ::: "memory");
        __builtin_amdgcn_sched_barrier(0);

        bf16x8 pf[2];
#pragma unroll
        for (int t = 0; t < 2; ++t)
            pf[t] = *(const bf16x8*)(P + SWZ(lc, t * 4 + lr));

        // PV: context += P @ K_tile (V = K hi, from pre-transposed kT)
        __builtin_amdgcn_s_setprio(1);
#pragma unroll
        for (int dt = 0; dt < 4; ++dt) {
#pragma unroll
            for (int t = 0; t < 2; ++t) {
                bf16x8 vf = *(const bf16x8*)(Vt + SWZ(dt * 16 + lc, t * 4 + lr));
                acc[dt] = __builtin_amdgcn_mfma_f32_16x16x32_bf16(pf[t], vf, acc[dt], 0, 0, 0);
            }
        }
        __builtin_amdgcn_s_setprio(0);

        if (kt < 15) __syncthreads();  // drains vmcnt (stage) + syncs buffers
        cur ^= 1;
    }

    // epilogue: one lsum reduction across the 16-lane row group (proven shfl butterfly)
#pragma unroll
    for (int r = 0; r < 4; ++r) {
#pragma unroll
        for (int d2 = 1; d2 < 16; d2 <<= 1) lsum[r] += __shfl_xor(lsum[r], d2, 64);
        float inv = (lsum[r] > 0.f) ? 1.f / lsum[r] : 0.f;
        int q = qt * 64 + w * 16 + lr * 4 + r;
#pragma unroll
        for (int dt = 0; dt < 4; ++dt)
            ctx[(((size_t)bh) * SS + q) * 64 + dt * 16 + lc] = acc[dt][r] * inv;
    }
}

// ---------------- row softmax for probs ----------------
__global__ __launch_bounds__(256) void softmax_rows(float* __restrict__ data) {
    int w = threadIdx.x >> 6, lane = threadIdx.x & 63;
    float* p = data + ((size_t)blockIdx.x * 4 + w) * SS;
    float4 v[4];
    float mx = -3e38f;
#pragma unroll
    for (int i = 0; i < 4; ++i) {
        v[i] = *(const float4*)(p + i * 256 + lane * 4);
        mx = fmaxf(mx, fmaxf(fmaxf(v[i].x, v[i].y), fmaxf(v[i].z, v[i].w)));
    }
#pragma unroll
    for (int d2 = 1; d2 < 64; d2 <<= 1) mx = fmaxf(mx, __shfl_xor(mx, d2, 64));
    float sum = 0.f;
#pragma unroll
    for (int i = 0; i < 4; ++i) {
        v[i].x = __expf(v[i].x - mx);
        v[i].y = __expf(v[i].y - mx);
        v[i].z = __expf(v[i].z - mx);
        v[i].w = __expf(v[i].w - mx);
        sum += v[i].x + v[i].y + v[i].z + v[i].w;
    }
#pragma unroll
    for (int d2 = 1; d2 < 64; d2 <<= 1) sum += __shfl_xor(sum, d2, 64);
    float inv = 1.f / sum;
#pragma unroll
    for (int i = 0; i < 4; ++i) {
        v[i].x *= inv; v[i].y *= inv; v[i].z *= inv; v[i].w *= inv;
        *(float4*)(p + i * 256 + lane * 4) = v[i];
    }
}

extern "C" void kernel_launch(void* const* d_in, const int* in_sizes, int n_in,
                              void* d_out, int out_size, void* d_ws, size_t ws_size,
                              hipStream_t stream) {
    const float* query = (const float*)d_in[0];
    const float* key   = (const float*)d_in[1];
    const int*   mask  = (const int*)d_in[2];
    const float* Wq    = (const float*)d_in[3];
    const float* bq    = (const float*)d_in[4];
    const float* Wk    = (const float*)d_in[5];
    const float* bk    = (const float*)d_in[6];
    const float* wcomb = (const float*)d_in[7];
    const float* bcomb = (const float*)d_in[8];
    float* probs = (float*)d_out;                          // (B,S,S)
    float* ctx   = (float*)d_out + (size_t)BB * SS * SS;   // (B,H,S,DK) flat

    char* ws = (char*)d_ws;
    const size_t MB = 1ull << 20;
    ushort* query_hi = (ushort*)(ws);             // [0,8)
    ushort* query_lo = (ushort*)(ws + 8 * MB);    // [8,16)
    ushort* key_hi   = (ushort*)(ws + 16 * MB);   // [16,24)
    ushort* key_lo   = (ushort*)(ws + 24 * MB);   // [24,32)
    ushort* WqTh     = (ushort*)(ws + 32 * MB);   // [32,34)
    ushort* WqTl     = (ushort*)(ws + 34 * MB);   // [34,36)
    ushort* WkTh     = (ushort*)(ws + 36 * MB);   // [36,38)
    ushort* WkTl     = (ushort*)(ws + 38 * MB);   // [38,40)
    ushort* qw_bf    = (ushort*)(ws + 40 * MB);   // [40,48)
    ushort* q_hi     = (ushort*)(ws + 48 * MB);   // [48,56)
    ushort* q_lo     = (ushort*)(ws + 56 * MB);   // [56,64)
    u64*    mbits    = (u64*)(ws + 64 * MB);      // [64,64.5)
    ushort* kT       = (ushort*)(ws + 65 * MB);   // [65,73)

    const bool bigws = ws_size >= 90 * MB;
    ushort* k_hi = bigws ? (ushort*)(ws + 73 * MB) : (ushort*)(ws);
    ushort* k_lo = bigws ? (ushort*)(ws + 81 * MB) : (ushort*)(ws + 8 * MB);

    cvt_split2<<<8192, 256, 0, stream>>>(query, key, query_hi, query_lo, key_hi, key_lo);
    transposeW_split<<<dim3(16, 16, 2), 256, 0, stream>>>(Wq, Wk, WqTh, WqTl, WkTh, WkTl);
    pack_mask<<<16384, 256, 0, stream>>>(mask, mbits, BB * SS * (SS / 64));

    if (bigws) {
        gemm_proj_f<<<dim3(8, 64, 2), 256, 0, stream>>>(
            query_hi, query_lo, key_hi, key_lo, WqTh, WqTl, WkTh, WkTl,
            bq, bk, wcomb, q_hi, q_lo, qw_bf, k_hi, k_lo, 0);
    } else {
        gemm_proj_f<<<dim3(8, 64, 1), 256, 0, stream>>>(
            query_hi, query_lo, key_hi, key_lo, WqTh, WqTl, WkTh, WkTl,
            bq, bk, wcomb, q_hi, q_lo, qw_bf, k_hi, k_lo, 0);
        gemm_proj_f<<<dim3(8, 64, 1), 256, 0, stream>>>(
            query_hi, query_lo, key_hi, key_lo, WqTh, WqTl, WkTh, WkTl,
            bq, bk, wcomb, q_hi, q_lo, qw_bf, k_hi, k_lo, 1);
    }

    transposeK<<<1024, 256, 0, stream>>>(k_hi, kT);

    attn_comb<<<1280, 256, 0, stream>>>(q_hi, q_lo, k_hi, k_lo, kT, mbits, ctx,
                                        qw_bf, k_hi, bcomb, probs);

    softmax_rows<<<1024, 256, 0, stream>>>(probs);
    (void)in_sizes; (void)n_in; (void)out_size;
}

// Round 15
// 199.301 us; speedup vs baseline: 2.3019x; 1.1163x over previous
//
#include <hip/hip_runtime.h>
#include <hip/hip_bf16.h>

#define BB 4
#define SS 1024
#define DD 1024
#define HH 16

typedef __attribute__((ext_vector_type(8))) short bf16x8;
typedef __attribute__((ext_vector_type(4))) float f32x4;
typedef unsigned int u32;
typedef unsigned long long u64;

__device__ __forceinline__ ushort f2bf(float f) {
    u32 u = __builtin_bit_cast(u32, f);
    u32 r = (u + 0x7fffu + ((u >> 16) & 1u)) >> 16;
    return (ushort)r;
}
__device__ __forceinline__ float bf2f(ushort h) {
    return __builtin_bit_cast(float, (u32)h << 16);
}

__device__ __forceinline__ void gload16(const ushort* g, ushort* l) {
    __builtin_amdgcn_global_load_lds(
        (const __attribute__((address_space(1))) u32*)(const void*)g,
        (__attribute__((address_space(3))) u32*)(void*)l, 16, 0, 0);
}

// ---------------- convert f32 -> bf16 hi + lo residual (q and k fused) ----------------
__global__ __launch_bounds__(256) void cvt_split2(
    const float* __restrict__ q, const float* __restrict__ k,
    ushort* __restrict__ qh, ushort* __restrict__ ql,
    ushort* __restrict__ kh, ushort* __restrict__ kl) {
    int bid = blockIdx.x;
    const float* in;
    ushort *hi, *lo;
    if (bid < 4096) { in = q; hi = qh; lo = ql; }
    else            { in = k; hi = kh; lo = kl; bid -= 4096; }
    int i = (bid * 256 + threadIdx.x) * 4;
    float4 v = *(const float4*)(in + i);
    ushort4 h, l;
    float* pv = (float*)&v;
    ushort* ph = (ushort*)&h;
    ushort* pl = (ushort*)&l;
#pragma unroll
    for (int j = 0; j < 4; ++j) {
        ushort hh = f2bf(pv[j]);
        ph[j] = hh;
        pl[j] = f2bf(pv[j] - bf2f(hh));
    }
    *(ushort4*)(hi + i) = h;
    *(ushort4*)(lo + i) = l;
}

// ---------------- transpose W (f32 DxD) -> bf16 W^T hi/lo ----------------
__global__ __launch_bounds__(256) void transposeW_split(
    const float* __restrict__ Wq, const float* __restrict__ Wk,
    ushort* __restrict__ WqTh, ushort* __restrict__ WqTl,
    ushort* __restrict__ WkTh, ushort* __restrict__ WkTl) {
    __shared__ float tile[64][65];
    const float* W = blockIdx.z ? Wk : Wq;
    ushort* WTh = blockIdx.z ? WkTh : WqTh;
    ushort* WTl = blockIdx.z ? WkTl : WqTl;
    int kb = blockIdx.y * 64, nb = blockIdx.x * 64;
    int tid = threadIdx.x;
    int tx = tid & 63, ty = tid >> 6;
#pragma unroll
    for (int i = 0; i < 16; ++i) {
        int kl = ty * 16 + i;
        tile[kl][tx] = W[(size_t)(kb + kl) * DD + nb + tx];
    }
    __syncthreads();
#pragma unroll
    for (int i = 0; i < 16; ++i) {
        int nl = ty * 16 + i;
        float v = tile[tx][nl];
        ushort hh = f2bf(v);
        size_t idx = (size_t)(nb + nl) * DD + kb + tx;
        WTh[idx] = hh;
        WTl[idx] = f2bf(v - bf2f(hh));
    }
}

// ---------------- pack mask to bits ----------------
__global__ __launch_bounds__(256) void pack_mask(const int* __restrict__ mask,
                                                 u64* __restrict__ bits, int nwords) {
    int gw = (int)((blockIdx.x * 256 + threadIdx.x) >> 6);
    int lane = threadIdx.x & 63;
    if (gw < nwords) {
        int v = mask[(size_t)gw * 64 + lane];
        u64 m = __ballot(v != 0);
        if (lane == 0) bits[gw] = m;
    }
}

// ---------------- transpose k_hi per head-tile into tiled kT ----------------
__global__ __launch_bounds__(256) void transposeK(const ushort* __restrict__ kh,
                                                  ushort* __restrict__ kT) {
    __shared__ ushort t[64 * 66];
    int blk = blockIdx.x;
    const ushort* src = kh + (size_t)blk * 4096;
    ushort* dst = kT + (size_t)blk * 4096;
    int tid = threadIdx.x;
#pragma unroll
    for (int i = 0; i < 2; ++i) {
        int c = tid + 256 * i;
        int r = c >> 3, col = (c & 7) << 3;
        uint4 v = *(const uint4*)(src + (size_t)c * 8);
        const uint* pv = (const uint*)&v;
        *(uint*)(t + r * 66 + col + 0) = pv[0];
        *(uint*)(t + r * 66 + col + 2) = pv[1];
        *(uint*)(t + r * 66 + col + 4) = pv[2];
        *(uint*)(t + r * 66 + col + 6) = pv[3];
    }
    __syncthreads();
#pragma unroll
    for (int i = 0; i < 2; ++i) {
        int c = tid + 256 * i;
        int d = c >> 3, k0 = (c & 7) << 3;
        uint4 o;
        ushort* po = (ushort*)&o;
#pragma unroll
        for (int j = 0; j < 8; ++j) po[j] = t[(k0 + j) * 66 + d];
        *(uint4*)(dst + d * 64 + k0) = o;
    }
}

// swizzled LDS frag address (ushort units): row rr, 16B-block bi
#define SWZ(rr, bi) (((rr) << 6) + ((((bi) ^ ((rr) & 7))) << 3))

// ---------------- split-precision projection GEMM, q & k fused via blockIdx.z ----------
// Staging now uses the proven swizzled pattern (linear LDS dest, pre-swizzled global
// source) and SWZ reads -> conflict-free ds_read_b128.
__global__ __launch_bounds__(256) void gemm_proj_f(
    const ushort* __restrict__ Aq_h, const ushort* __restrict__ Aq_l,
    const ushort* __restrict__ Ak_h, const ushort* __restrict__ Ak_l,
    const ushort* __restrict__ Bq_h, const ushort* __restrict__ Bq_l,
    const ushort* __restrict__ Bk_h, const ushort* __restrict__ Bk_l,
    const float* __restrict__ bq, const float* __restrict__ bk,
    const float* __restrict__ wcomb,
    ushort* __restrict__ Cq_hi, ushort* __restrict__ Cq_lo, ushort* __restrict__ Cw,
    ushort* __restrict__ Ck_hi, ushort* __restrict__ Ck_lo, int mode_base) {
    __shared__ __align__(16) ushort Ash[64 * 64];
    __shared__ __align__(16) ushort Asl[64 * 64];
    __shared__ __align__(16) ushort Bsh[128 * 64];
    __shared__ __align__(16) ushort Bsl[128 * 64];
    const int mode = blockIdx.z + mode_base;
    const ushort* Ah = mode ? Ak_h : Aq_h;
    const ushort* Al = mode ? Ak_l : Aq_l;
    const ushort* Bh = mode ? Bk_h : Bq_h;
    const ushort* Bl = mode ? Bk_l : Bq_l;
    const float* bias = mode ? bk : bq;
    ushort* Chi = mode ? Ck_hi : Cq_hi;
    ushort* Clo = mode ? Ck_lo : Cq_lo;
    const int tn = blockIdx.x, tm = blockIdx.y;
    const int tid = threadIdx.x, lane = tid & 63, w = tid >> 6;
    const int lr = lane >> 4, lc = lane & 15;
    const int srow = lane >> 3;                       // 0..7 within chunk
    const int sblk = (lane & 7) ^ ((lane >> 3) & 7);  // swizzled 16B block
    f32x4 acc[8];
#pragma unroll
    for (int n = 0; n < 8; ++n) acc[n] = (f32x4){0.f, 0.f, 0.f, 0.f};

    for (int kt = 0; kt < DD; kt += 64) {
        __syncthreads();
#pragma unroll
        for (int i = 0; i < 2; ++i) {
            int ch = (w << 1) + i;                    // chunk 0..7 (8 rows each)
            int row = (ch << 3) + srow;               // 0..63
            size_t g = (size_t)(tm * 64 + row) * DD + kt + sblk * 8;
            gload16(Ah + g, Ash + ch * 512);
            gload16(Al + g, Asl + ch * 512);
        }
#pragma unroll
        for (int i = 0; i < 4; ++i) {
            int ch = (w << 2) + i;                    // chunk 0..15
            int row = (ch << 3) + srow;               // 0..127
            size_t g = (size_t)(tn * 128 + row) * DD + kt + sblk * 8;
            gload16(Bh + g, Bsh + ch * 512);
            gload16(Bl + g, Bsl + ch * 512);
        }
        __syncthreads();
#pragma unroll
        for (int t = 0; t < 2; ++t) {
            int aoff = SWZ(w * 16 + lc, t * 4 + lr);
            bf16x8 afh = *(const bf16x8*)(Ash + aoff);
            bf16x8 afl = *(const bf16x8*)(Asl + aoff);
#pragma unroll
            for (int n = 0; n < 8; ++n) {
                int boff = SWZ(n * 16 + lc, t * 4 + lr);
                bf16x8 bfh = *(const bf16x8*)(Bsh + boff);
                bf16x8 bfl = *(const bf16x8*)(Bsl + boff);
                acc[n] = __builtin_amdgcn_mfma_f32_16x16x32_bf16(afh, bfh, acc[n], 0, 0, 0);
                acc[n] = __builtin_amdgcn_mfma_f32_16x16x32_bf16(afh, bfl, acc[n], 0, 0, 0);
                acc[n] = __builtin_amdgcn_mfma_f32_16x16x32_bf16(afl, bfh, acc[n], 0, 0, 0);
            }
        }
    }
#pragma unroll
    for (int n = 0; n < 8; ++n) {
        int gcol = tn * 128 + n * 16 + lc;
#pragma unroll
        for (int r = 0; r < 4; ++r) {
            int grow = tm * 64 + w * 16 + lr * 4 + r;
            float v = acc[n][r] + bias[gcol];
            size_t idx = (size_t)grow * DD + gcol;
            ushort hh = f2bf(v);
            Chi[idx] = hh;
            Clo[idx] = f2bf(v - bf2f(hh));
            if (mode == 0) Cw[idx] = f2bf(v * wcomb[(grow >> 6) & 15]);
        }
    }
}

// ---------------- FAT kernel: gemm_comb (blocks 0..255) || attn (blocks 256..1279) ----
// attn LDS = 48 KB exactly (3 blocks/CU): P aliases the dead kh tile after QK^T,
// guarded by a RAW s_barrier (no vmcnt drain -> prefetch stays in flight).
__global__ __launch_bounds__(256) void attn_comb(
    const ushort* __restrict__ qh_, const ushort* __restrict__ ql_,
    const ushort* __restrict__ kh_, const ushort* __restrict__ kl_,
    const ushort* __restrict__ kT_, const u64* __restrict__ mbits,
    float* __restrict__ ctx,
    const ushort* __restrict__ Aq, const ushort* __restrict__ Bk,
    const float* __restrict__ bcomb, float* __restrict__ probs) {
    __shared__ __align__(16) ushort shm[24576];  // 49,152 B
    const int bid = blockIdx.x;
    const int tid = threadIdx.x, lane = tid & 63, w = tid >> 6;
    const int lr = lane >> 4, lc = lane & 15;

    if (bid < 256) {
        // ---------------- combined-scores GEMM (swizzled staging; r13/r14-proven) -----
        ushort* As = shm;           // 128x64 swizzled
        ushort* Bs = shm + 8192;
        const int tn = bid & 7, tm = (bid >> 3) & 7, bz = bid >> 6;
        const ushort* Ab = Aq + (size_t)bz * SS * DD;
        const ushort* Bb = Bk + (size_t)bz * SS * DD;
        const int wm = w >> 1, wn = w & 1;
        f32x4 acc[4][4];
#pragma unroll
        for (int m = 0; m < 4; ++m)
#pragma unroll
            for (int n = 0; n < 4; ++n) acc[m][n] = (f32x4){0.f, 0.f, 0.f, 0.f};

        for (int h = 0; h < HH; ++h) {
            __syncthreads();
            const ushort* Asrc = Ab + (size_t)h * 65536 + tm * 8192;
            const ushort* Bsrc = Bb + (size_t)h * 65536 + tn * 8192;
#pragma unroll
            for (int i = 0; i < 4; ++i) {
                int ch = (w << 2) + i;                      // chunk 0..15 (1024B)
                int row = (ch << 3) + (lane >> 3);          // 0..127
                int blkk = (lane & 7) ^ ((lane >> 3) & 7);  // swizzled 16B block
                size_t g = (size_t)row * 64 + blkk * 8;
                gload16(Asrc + g, As + ch * 512);
                gload16(Bsrc + g, Bs + ch * 512);
            }
            __syncthreads();
#pragma unroll
            for (int t = 0; t < 2; ++t) {
                bf16x8 af[4], bfr[4];
#pragma unroll
                for (int m = 0; m < 4; ++m)
                    af[m] = *(const bf16x8*)(As + SWZ(wm * 64 + m * 16 + lc, t * 4 + lr));
#pragma unroll
                for (int n = 0; n < 4; ++n)
                    bfr[n] = *(const bf16x8*)(Bs + SWZ(wn * 64 + n * 16 + lc, t * 4 + lr));
#pragma unroll
                for (int m = 0; m < 4; ++m)
#pragma unroll
                    for (int n = 0; n < 4; ++n)
                        acc[m][n] = __builtin_amdgcn_mfma_f32_16x16x32_bf16(af[m], bfr[n], acc[m][n], 0, 0, 0);
            }
        }
        float b0 = bcomb[0];
#pragma unroll
        for (int m = 0; m < 4; ++m) {
            int grow0 = tm * 128 + wm * 64 + m * 16 + lr * 4;
#pragma unroll
            for (int n = 0; n < 4; ++n) {
                int gcol = tn * 128 + wn * 64 + n * 16 + lc;
#pragma unroll
                for (int r = 0; r < 4; ++r)
                    probs[(size_t)bz * SS * SS + (size_t)(grow0 + r) * SS + gcol] = acc[m][n][r] + b0;
            }
        }
        return;
    }

    // ---------------- flash attention (V = K): r14-proven body ----------------
    const int abid = bid - 256;
    const int qt = abid & 15, h = (abid >> 4) & 15, b = abid >> 8;
    ushort* KbBase = shm;          // [2][3][4096] = 48 KB
    const int bh = b * HH + h;
    const size_t headbase = (size_t)bh * (SS * 64);

    auto KB = [&](int buf, int j) -> ushort* { return KbBase + (buf * 3 + j) * 4096; };
    auto stage = [&](int buf, int kt) {
#pragma unroll
        for (int i = 0; i < 2; ++i) {
            int ch = (w << 1) + i;
            int row = (ch << 3) + (lane >> 3);
            int blkk = (lane & 7) ^ ((lane >> 3) & 7);
            size_t g = ((size_t)bh * 16 + kt) * 4096 + (size_t)row * 64 + blkk * 8;
            gload16(kh_ + g, KB(buf, 0) + ch * 512);
            gload16(kl_ + g, KB(buf, 1) + ch * 512);
            gload16(kT_ + g, KB(buf, 2) + ch * 512);
        }
    };

    bf16x8 qfh[2], qfl[2];
    {
        size_t rowoff = headbase + (size_t)(qt * 64 + w * 16 + lc) * 64;
#pragma unroll
        for (int t = 0; t < 2; ++t) {
            qfh[t] = *(const bf16x8*)(qh_ + rowoff + t * 32 + lr * 8);
            qfl[t] = *(const bf16x8*)(ql_ + rowoff + t * 32 + lr * 8);
        }
    }
    f32x4 acc[4];
#pragma unroll
    for (int dt = 0; dt < 4; ++dt) acc[dt] = (f32x4){0.f, 0.f, 0.f, 0.f};
    float mrow[4] = {-3e38f, -3e38f, -3e38f, -3e38f};
    float lsum[4] = {0.f, 0.f, 0.f, 0.f};  // per-lane partial (scale is row-uniform)

    stage(0, 0);
    __syncthreads();
    int cur = 0;

    for (int kt = 0; kt < 16; ++kt) {
        if (kt < 15) stage(cur ^ 1, kt + 1);  // prefetch next (hidden under compute)

        const ushort* Bh = KB(cur, 0);
        const ushort* Bl = KB(cur, 1);
        const ushort* Vt = KB(cur, 2);

        // QK^T (split precision): s = qh*kh + qh*kl + ql*kh
        f32x4 sc[4];
#pragma unroll
        for (int nt = 0; nt < 4; ++nt) {
            f32x4 z = (f32x4){0.f, 0.f, 0.f, 0.f};
            __builtin_amdgcn_s_setprio(1);
#pragma unroll
            for (int t = 0; t < 2; ++t) {
                bf16x8 kfh = *(const bf16x8*)(Bh + SWZ(nt * 16 + lc, t * 4 + lr));
                bf16x8 kfl = *(const bf16x8*)(Bl + SWZ(nt * 16 + lc, t * 4 + lr));
                z = __builtin_amdgcn_mfma_f32_16x16x32_bf16(qfh[t], kfh, z, 0, 0, 0);
                z = __builtin_amdgcn_mfma_f32_16x16x32_bf16(qfh[t], kfl, z, 0, 0, 0);
                z = __builtin_amdgcn_mfma_f32_16x16x32_bf16(qfl[t], kfh, z, 0, 0, 0);
            }
            __builtin_amdgcn_s_setprio(0);
            sc[nt] = z;
        }

        // mask + online softmax: rmax shfl (proven), rsum deferred to per-lane partial
#pragma unroll
        for (int r = 0; r < 4; ++r) {
            u64 wbit = mbits[((size_t)b * SS + qt * 64 + w * 16 + lr * 4 + r) * 16 + kt];
            float rmax = -3e38f;
#pragma unroll
            for (int nt = 0; nt < 4; ++nt) {
                int kkloc = nt * 16 + lc;
                float v = sc[nt][r];
                v = ((wbit >> kkloc) & 1ULL) ? v : -3e38f;
                sc[nt][r] = v;
                rmax = fmaxf(rmax, v);
            }
#pragma unroll
            for (int d2 = 1; d2 < 16; d2 <<= 1) rmax = fmaxf(rmax, __shfl_xor(rmax, d2, 64));
            float mnew = fmaxf(mrow[r], rmax);
            float scale = __expf(mrow[r] - mnew);
            float rsum = 0.f;
#pragma unroll
            for (int nt = 0; nt < 4; ++nt) {
                float p = __expf(sc[nt][r] - mnew);
                sc[nt][r] = p;
                rsum += p;
            }
            lsum[r] = lsum[r] * scale + rsum;  // per-lane; summed across lanes at end
            mrow[r] = mnew;
#pragma unroll
            for (int dt = 0; dt < 4; ++dt) acc[dt][r] *= scale;
        }

        // RAW barrier: all waves' kh reads done before P overwrites kh.
        // (No vmcnt drain -> the stage() prefetch stays in flight.)
        __builtin_amdgcn_s_barrier();
        __builtin_amdgcn_sched_barrier(0);

        // P -> aliased kh slice (wave-private 16x64, SWZ-swizzled), RNE pack (proven)
        ushort* P = KB(cur, 0) + w * 1024;
#pragma unroll
        for (int nt = 0; nt < 4; ++nt)
#pragma unroll
            for (int r = 0; r < 4; ++r) {
                int lrow = lr * 4 + r;
                P[SWZ(lrow, nt * 2 + (lc >> 3)) + (lc & 7)] = f2bf(sc[nt][r]);
            }
        asm volatile("s_waitcnt lgkmcnt(0)" ::: "memory");
        __builtin_amdgcn_sched_barrier(0);

        bf16x8 pf[2];
#pragma unroll
        for (int t = 0; t < 2; ++t)
            pf[t] = *(const bf16x8*)(P + SWZ(lc, t * 4 + lr));

        // PV: context += P @ K_tile (V = K hi, from pre-transposed kT)
        __builtin_amdgcn_s_setprio(1);
#pragma unroll
        for (int dt = 0; dt < 4; ++dt) {
#pragma unroll
            for (int t = 0; t < 2; ++t) {
                bf16x8 vf = *(const bf16x8*)(Vt + SWZ(dt * 16 + lc, t * 4 + lr));
                acc[dt] = __builtin_amdgcn_mfma_f32_16x16x32_bf16(pf[t], vf, acc[dt], 0, 0, 0);
            }
        }
        __builtin_amdgcn_s_setprio(0);

        if (kt < 15) __syncthreads();  // drains vmcnt (stage) + syncs buffers
        cur ^= 1;
    }

    // epilogue: one lsum reduction across the 16-lane row group (proven shfl butterfly)
#pragma unroll
    for (int r = 0; r < 4; ++r) {
#pragma unroll
        for (int d2 = 1; d2 < 16; d2 <<= 1) lsum[r] += __shfl_xor(lsum[r], d2, 64);
        float inv = (lsum[r] > 0.f) ? 1.f / lsum[r] : 0.f;
        int q = qt * 64 + w * 16 + lr * 4 + r;
#pragma unroll
        for (int dt = 0; dt < 4; ++dt)
            ctx[(((size_t)bh) * SS + q) * 64 + dt * 16 + lc] = acc[dt][r] * inv;
    }
}

// ---------------- row softmax for probs ----------------
__global__ __launch_bounds__(256) void softmax_rows(float* __restrict__ data) {
    int w = threadIdx.x >> 6, lane = threadIdx.x & 63;
    float* p = data + ((size_t)blockIdx.x * 4 + w) * SS;
    float4 v[4];
    float mx = -3e38f;
#pragma unroll
    for (int i = 0; i < 4; ++i) {
        v[i] = *(const float4*)(p + i * 256 + lane * 4);
        mx = fmaxf(mx, fmaxf(fmaxf(v[i].x, v[i].y), fmaxf(v[i].z, v[i].w)));
    }
#pragma unroll
    for (int d2 = 1; d2 < 64; d2 <<= 1) mx = fmaxf(mx, __shfl_xor(mx, d2, 64));
    float sum = 0.f;
#pragma unroll
    for (int i = 0; i < 4; ++i) {
        v[i].x = __expf(v[i].x - mx);
        v[i].y = __expf(v[i].y - mx);
        v[i].z = __expf(v[i].z - mx);
        v[i].w = __expf(v[i].w - mx);
        sum += v[i].x + v[i].y + v[i].z + v[i].w;
    }
#pragma unroll
    for (int d2 = 1; d2 < 64; d2 <<= 1) sum += __shfl_xor(sum, d2, 64);
    float inv = 1.f / sum;
#pragma unroll
    for (int i = 0; i < 4; ++i) {
        v[i].x *= inv; v[i].y *= inv; v[i].z *= inv; v[i].w *= inv;
        *(float4*)(p + i * 256 + lane * 4) = v[i];
    }
}

extern "C" void kernel_launch(void* const* d_in, const int* in_sizes, int n_in,
                              void* d_out, int out_size, void* d_ws, size_t ws_size,
                              hipStream_t stream) {
    const float* query = (const float*)d_in[0];
    const float* key   = (const float*)d_in[1];
    const int*   mask  = (const int*)d_in[2];
    const float* Wq    = (const float*)d_in[3];
    const float* bq    = (const float*)d_in[4];
    const float* Wk    = (const float*)d_in[5];
    const float* bk    = (const float*)d_in[6];
    const float* wcomb = (const float*)d_in[7];
    const float* bcomb = (const float*)d_in[8];
    float* probs = (float*)d_out;                          // (B,S,S)
    float* ctx   = (float*)d_out + (size_t)BB * SS * SS;   // (B,H,S,DK) flat

    char* ws = (char*)d_ws;
    const size_t MB = 1ull << 20;
    ushort* query_hi = (ushort*)(ws);             // [0,8)
    ushort* query_lo = (ushort*)(ws + 8 * MB);    // [8,16)
    ushort* key_hi   = (ushort*)(ws + 16 * MB);   // [16,24)
    ushort* key_lo   = (ushort*)(ws + 24 * MB);   // [24,32)
    ushort* WqTh     = (ushort*)(ws + 32 * MB);   // [32,34)
    ushort* WqTl     = (ushort*)(ws + 34 * MB);   // [34,36)
    ushort* WkTh     = (ushort*)(ws + 36 * MB);   // [36,38)
    ushort* WkTl     = (ushort*)(ws + 38 * MB);   // [38,40)
    ushort* qw_bf    = (ushort*)(ws + 40 * MB);   // [40,48)
    ushort* q_hi     = (ushort*)(ws + 48 * MB);   // [48,56)
    ushort* q_lo     = (ushort*)(ws + 56 * MB);   // [56,64)
    u64*    mbits    = (u64*)(ws + 64 * MB);      // [64,64.5)
    ushort* kT       = (ushort*)(ws + 65 * MB);   // [65,73)

    const bool bigws = ws_size >= 90 * MB;
    ushort* k_hi = bigws ? (ushort*)(ws + 73 * MB) : (ushort*)(ws);
    ushort* k_lo = bigws ? (ushort*)(ws + 81 * MB) : (ushort*)(ws + 8 * MB);

    cvt_split2<<<8192, 256, 0, stream>>>(query, key, query_hi, query_lo, key_hi, key_lo);
    transposeW_split<<<dim3(16, 16, 2), 256, 0, stream>>>(Wq, Wk, WqTh, WqTl, WkTh, WkTl);
    pack_mask<<<16384, 256, 0, stream>>>(mask, mbits, BB * SS * (SS / 64));

    if (bigws) {
        gemm_proj_f<<<dim3(8, 64, 2), 256, 0, stream>>>(
            query_hi, query_lo, key_hi, key_lo, WqTh, WqTl, WkTh, WkTl,
            bq, bk, wcomb, q_hi, q_lo, qw_bf, k_hi, k_lo, 0);
    } else {
        gemm_proj_f<<<dim3(8, 64, 1), 256, 0, stream>>>(
            query_hi, query_lo, key_hi, key_lo, WqTh, WqTl, WkTh, WkTl,
            bq, bk, wcomb, q_hi, q_lo, qw_bf, k_hi, k_lo, 0);
        gemm_proj_f<<<dim3(8, 64, 1), 256, 0, stream>>>(
            query_hi, query_lo, key_hi, key_lo, WqTh, WqTl, WkTh, WkTl,
            bq, bk, wcomb, q_hi, q_lo, qw_bf, k_hi, k_lo, 1);
    }

    transposeK<<<1024, 256, 0, stream>>>(k_hi, kT);

    attn_comb<<<1280, 256, 0, stream>>>(q_hi, q_lo, k_hi, k_lo, kT, mbits, ctx,
                                        qw_bf, k_hi, bcomb, probs);

    softmax_rows<<<1024, 256, 0, stream>>>(probs);
    (void)in_sizes; (void)n_in; (void)out_size;
}